// Round 1
// baseline (961.011 us; speedup 1.0000x reference)
//
#include <hip/hip_runtime.h>
#include <hip/hip_bf16.h>
#include <stdint.h>

typedef __hip_bfloat16 bf16;
typedef __attribute__((ext_vector_type(8))) short bf16x8;   // 8 bf16 = 4 VGPRs
typedef __attribute__((ext_vector_type(4))) float f32x4;

#define DEVI __device__ __forceinline__

static constexpr float FACTOR = 0.0625f;  // 0.5 / sqrt(64)

DEVI unsigned short bfbits(float x) {
  return __builtin_bit_cast(unsigned short, __float2bfloat16(x));
}

// ---------------------------------------------------------------- converts
__global__ void cvt_plain(const float* __restrict__ src, bf16* __restrict__ dst, int n) {
  int i = (blockIdx.x * 256 + threadIdx.x) * 4;
  if (i >= n) return;
  float4 v = *reinterpret_cast<const float4*>(src + i);
  union { unsigned short u[4]; uint64_t d; } t;
  t.u[0] = bfbits(v.x); t.u[1] = bfbits(v.y); t.u[2] = bfbits(v.z); t.u[3] = bfbits(v.w);
  *reinterpret_cast<uint64_t*>(dst + i) = t.d;
}

// V [B,N,3,512] f32  ->  Vbf [3][B*N][512] bf16  (c-major planes so GEMM rows are n-contiguous)
__global__ void cvt_vperm(const float* __restrict__ src, bf16* __restrict__ dst) {
  int g = blockIdx.x * 256 + threadIdx.x;          // 3,145,728 groups of 4
  int k4  = (g & 127) * 4;
  int rem = g >> 7;                                // (b*2048+n)*3 + c
  int c  = rem % 3;
  int bn = rem / 3;
  float4 v = *reinterpret_cast<const float4*>(src + (size_t)rem * 512 + k4);
  union { unsigned short u[4]; uint64_t d; } t;
  t.u[0] = bfbits(v.x); t.u[1] = bfbits(v.y); t.u[2] = bfbits(v.z); t.u[3] = bfbits(v.w);
  *reinterpret_cast<uint64_t*>(dst + ((size_t)c * 8192 + bn) * 512 + k4) = t.d;
}

__global__ void cvt_weights(const float* __restrict__ wq, const float* __restrict__ wk,
                            const float* __restrict__ wv, const float* __restrict__ wvv,
                            const float* __restrict__ wo, const float* __restrict__ wvo,
                            bf16* __restrict__ dst) {
  int blk = blockIdx.x;
  const float* s; int off;
  if      (blk < 1024) { s = wq  + blk * 1024;          off = 0       + blk * 1024; }
  else if (blk < 2048) { s = wk  + (blk - 1024) * 1024; off = 1048576 + (blk - 1024) * 1024; }
  else if (blk < 2304) { s = wv  + (blk - 2048) * 1024; off = 2097152 + (blk - 2048) * 1024; }
  else if (blk < 2560) { s = wvv + (blk - 2304) * 1024; off = 2359296 + (blk - 2304) * 1024; }
  else if (blk < 2816) { s = wo  + (blk - 2560) * 1024; off = 2621440 + (blk - 2560) * 1024; }
  else                 { s = wvo + (blk - 2816) * 1024; off = 2883584 + (blk - 2816) * 1024; }
  int i = threadIdx.x * 4;
  float4 v = *reinterpret_cast<const float4*>(s + i);
  union { unsigned short u[4]; uint64_t d; } t;
  t.u[0] = bfbits(v.x); t.u[1] = bfbits(v.y); t.u[2] = bfbits(v.z); t.u[3] = bfbits(v.w);
  *reinterpret_cast<uint64_t*>(dst + off + i) = t.d;
}

// ---------------------------------------------------------------- GEMM  C = A @ W^T (+bias)
// A [M,512] bf16 row-major, W [Nc,512] bf16 row-major. 128x128 tile, BK=32, 4 waves.
// MODE 0: -> Q [b,h,n,256] bf16, (acc+bq)*FACTOR      MODE 1: -> K same layout, +bk
// MODE 2: Hv -> Vt[(bh*256+t)*2048+n], +bv            MODE 3: Vv -> Vt[(bh*256+64+c*64+t)*2048+n]
// MODE 4: -> d_out f32 (+bo)                          MODE 5: -> d_out+4194304 f32
template<int MODE>
__global__ __launch_bounds__(256, 2) void gemm_bt(const bf16* __restrict__ A,
                                                  const bf16* __restrict__ W,
                                                  const float* __restrict__ bias,
                                                  void* __restrict__ outp) {
  constexpr int K = 512;
  __shared__ bf16 As[128][40];   // 80B row stride: bank-conflict-free-ish (2-way)
  __shared__ bf16 Bs[128][40];
  const int tid = threadIdx.x;
  const int wid = tid >> 6, lane = tid & 63;
  const int lr = lane & 15, lg = lane >> 4;
  const int wr = wid >> 1, wc = wid & 1;
  const int bm = blockIdx.y * 128, bn = blockIdx.x * 128;
  const int srow = tid >> 2;
  const int scol = (tid & 3) * 8;
  const bf16* Ap = A + (size_t)(bm + srow) * K + scol;
  const bf16* Wp = W + (size_t)(bn + srow) * K + scol;

  f32x4 acc[4][4];
#pragma unroll
  for (int m = 0; m < 4; m++)
#pragma unroll
    for (int n = 0; n < 4; n++) acc[m][n] = (f32x4){0.f, 0.f, 0.f, 0.f};

  bf16x8 a0 = *reinterpret_cast<const bf16x8*>(Ap);
  bf16x8 a1 = *reinterpret_cast<const bf16x8*>(Ap + 64 * K);
  bf16x8 b0 = *reinterpret_cast<const bf16x8*>(Wp);
  bf16x8 b1 = *reinterpret_cast<const bf16x8*>(Wp + 64 * K);

  for (int kt = 0; kt < 16; ++kt) {
    __syncthreads();
    *reinterpret_cast<bf16x8*>(&As[srow][scol])      = a0;
    *reinterpret_cast<bf16x8*>(&As[srow + 64][scol]) = a1;
    *reinterpret_cast<bf16x8*>(&Bs[srow][scol])      = b0;
    *reinterpret_cast<bf16x8*>(&Bs[srow + 64][scol]) = b1;
    __syncthreads();
    if (kt < 15) {
      a0 = *reinterpret_cast<const bf16x8*>(Ap + (kt + 1) * 32);
      a1 = *reinterpret_cast<const bf16x8*>(Ap + (kt + 1) * 32 + 64 * K);
      b0 = *reinterpret_cast<const bf16x8*>(Wp + (kt + 1) * 32);
      b1 = *reinterpret_cast<const bf16x8*>(Wp + (kt + 1) * 32 + 64 * K);
    }
    bf16x8 af[4], bfr[4];
#pragma unroll
    for (int m = 0; m < 4; m++)
      af[m] = *reinterpret_cast<const bf16x8*>(&As[wr * 64 + m * 16 + lr][lg * 8]);
#pragma unroll
    for (int n = 0; n < 4; n++)
      bfr[n] = *reinterpret_cast<const bf16x8*>(&Bs[wc * 64 + n * 16 + lr][lg * 8]);
#pragma unroll
    for (int m = 0; m < 4; m++)
#pragma unroll
      for (int n = 0; n < 4; n++)
        acc[m][n] = __builtin_amdgcn_mfma_f32_16x16x32_bf16(af[m], bfr[n], acc[m][n], 0, 0, 0);
  }

  // epilogue: C/D layout col = lane&15, row = (lane>>4)*4 + reg   [m89]
#pragma unroll
  for (int m = 0; m < 4; m++) {
#pragma unroll
    for (int n = 0; n < 4; n++) {
      const int col  = bn + wc * 64 + n * 16 + lr;
      const int row0 = bm + wr * 64 + m * 16 + lg * 4;
      if constexpr (MODE == 0 || MODE == 1) {
        bf16* out = (bf16*)outp;
        const float bb = bias[col];
        const int hh = col >> 8, t = col & 255;
#pragma unroll
        for (int q = 0; q < 4; q++) {
          const int row = row0 + q;
          const int b = row >> 11, nn = row & 2047;
          float v = acc[m][n][q] + bb;
          if constexpr (MODE == 0) v *= FACTOR;
          out[(size_t)((b * 8 + hh) * 2048 + nn) * 256 + t] = __float2bfloat16(v);
        }
      } else if constexpr (MODE == 2) {
        bf16* out = (bf16*)outp;
        const float bb = bias[col];
        const int hh = col >> 6, t = col & 63;
        const int b = row0 >> 11, nn = row0 & 2047;
        union { unsigned short u[4]; uint64_t d; } pk;
#pragma unroll
        for (int q = 0; q < 4; q++) pk.u[q] = bfbits(acc[m][n][q] + bb);
        *reinterpret_cast<uint64_t*>(out + ((size_t)((b * 8 + hh) * 256 + t)) * 2048 + nn) = pk.d;
      } else if constexpr (MODE == 3) {
        bf16* out = (bf16*)outp;
        const int hh = col >> 6, t = col & 63;
        const int c = row0 >> 13, b = (row0 >> 11) & 3, nn = row0 & 2047;
        union { unsigned short u[4]; uint64_t d; } pk;
#pragma unroll
        for (int q = 0; q < 4; q++) pk.u[q] = bfbits(acc[m][n][q]);
        *reinterpret_cast<uint64_t*>(out + ((size_t)((b * 8 + hh) * 256 + 64 + c * 64 + t)) * 2048 + nn) = pk.d;
      } else {
        float* out = (float*)outp;
        const float bb = (MODE == 4) ? bias[col] : 0.f;
#pragma unroll
        for (int q = 0; q < 4; q++) out[(size_t)(row0 + q) * 512 + col] = acc[m][n][q] + bb;
      }
    }
  }
}

// ---------------------------------------------------------------- flash attention
// grid (h=8, qt=16, b=4), block 512 (8 waves, 16 q-rows each). Q prescaled by FACTOR.
__global__ __launch_bounds__(512, 2) void attn_kernel(
    const bf16* __restrict__ Qg, const bf16* __restrict__ Kg, const bf16* __restrict__ Vtg,
    const float* __restrict__ Dm, const float* __restrict__ rbf, const int* __restrict__ mask,
    bf16* __restrict__ Hres, bf16* __restrict__ Vres) {
  __shared__ bf16 Ks[32][264];      // [key][dim] padded: 528B rows
  __shared__ bf16 Vs[256][40];      // [dim][key] padded: 80B rows
  __shared__ bf16 Ps[8][16][40];    // per-wave P^T staging [q][key]

  const int h = blockIdx.x, qt = blockIdx.y, b = blockIdx.z;
  const int bh = b * 8 + h;
  const int tid = threadIdx.x, wid = tid >> 6, lane = tid & 63;
  const int lr = lane & 15, lg = lane >> 4;
  const int q0 = qt * 128 + wid * 16;

  const bf16* Qb = Qg + (size_t)bh * 2048 * 256;
  const bf16* Kb = Kg + (size_t)bh * 2048 * 256;
  const bf16* Vb = Vtg + (size_t)bh * 256 * 2048;
  const float* Db = Dm + (size_t)b * 2048 * 2048;
  const float* Rb = rbf + (size_t)b * 2048 * 2048;
  const int* mb = mask + b * 2048;

  bf16x8 qf[8];
#pragma unroll
  for (int kc = 0; kc < 8; kc++)
    qf[kc] = *reinterpret_cast<const bf16x8*>(Qb + (size_t)(q0 + lr) * 256 + kc * 32 + lg * 8);

  f32x4 O[16];
#pragma unroll
  for (int dc = 0; dc < 16; dc++) O[dc] = (f32x4){0.f, 0.f, 0.f, 0.f};
  float mrun[4], lrun[4];
#pragma unroll
  for (int q = 0; q < 4; q++) { mrun[q] = -INFINITY; lrun[q] = 0.f; }

  const int krow = tid >> 5, kchk = (tid & 31) * 8;   // K tile staging (16 rows x2)
  const int vrow = tid >> 2, vchk = (tid & 3) * 8;    // V tile staging (128 rows x2)

  bf16x8 ka  = *reinterpret_cast<const bf16x8*>(Kb + (size_t)krow * 256 + kchk);
  bf16x8 kb2 = *reinterpret_cast<const bf16x8*>(Kb + (size_t)(krow + 16) * 256 + kchk);
  bf16x8 va  = *reinterpret_cast<const bf16x8*>(Vb + (size_t)vrow * 2048 + vchk);
  bf16x8 vb2 = *reinterpret_cast<const bf16x8*>(Vb + (size_t)(vrow + 128) * 2048 + vchk);

  for (int kt = 0; kt < 64; ++kt) {
    const int k0 = kt * 32;
    __syncthreads();
    *reinterpret_cast<bf16x8*>(&Ks[krow][kchk])       = ka;
    *reinterpret_cast<bf16x8*>(&Ks[krow + 16][kchk])  = kb2;
    *reinterpret_cast<bf16x8*>(&Vs[vrow][vchk])       = va;
    *reinterpret_cast<bf16x8*>(&Vs[vrow + 128][vchk]) = vb2;
    __syncthreads();
    if (kt < 63) {
      const int k1 = k0 + 32;
      ka  = *reinterpret_cast<const bf16x8*>(Kb + (size_t)(k1 + krow) * 256 + kchk);
      kb2 = *reinterpret_cast<const bf16x8*>(Kb + (size_t)(k1 + krow + 16) * 256 + kchk);
      va  = *reinterpret_cast<const bf16x8*>(Vb + (size_t)vrow * 2048 + k1 + vchk);
      vb2 = *reinterpret_cast<const bf16x8*>(Vb + (size_t)(vrow + 128) * 2048 + k1 + vchk);
    }

    // S = Q @ K^T (Q prescaled by FACTOR)
    f32x4 s0 = (f32x4){0.f, 0.f, 0.f, 0.f}, s1 = (f32x4){0.f, 0.f, 0.f, 0.f};
#pragma unroll
    for (int kc = 0; kc < 8; kc++) {
      bf16x8 k0f = *reinterpret_cast<const bf16x8*>(&Ks[lr][kc * 32 + lg * 8]);
      bf16x8 k1f = *reinterpret_cast<const bf16x8*>(&Ks[16 + lr][kc * 32 + lg * 8]);
      s0 = __builtin_amdgcn_mfma_f32_16x16x32_bf16(qf[kc], k0f, s0, 0, 0, 0);
      s1 = __builtin_amdgcn_mfma_f32_16x16x32_bf16(qf[kc], k1f, s1, 0, 0, 0);
    }

    const int col0 = k0 + lr, col1 = k0 + 16 + lr;
    const int mk0 = mb[col0], mk1 = mb[col1];
    float sc0[4], sc1[4];
#pragma unroll
    for (int q = 0; q < 4; q++) {
      const size_t ro = (size_t)(q0 + lg * 4 + q) * 2048;
      sc0[q] = mk0 ? s0[q] + Rb[ro + col0] + Db[ro + col0] : -INFINITY;
      sc1[q] = mk1 ? s1[q] + Rb[ro + col1] + Db[ro + col1] : -INFINITY;
    }

#pragma unroll
    for (int q = 0; q < 4; q++) {
      float mx = fmaxf(sc0[q], sc1[q]);
      mx = fmaxf(mx, __shfl_xor(mx, 1));
      mx = fmaxf(mx, __shfl_xor(mx, 2));
      mx = fmaxf(mx, __shfl_xor(mx, 4));
      mx = fmaxf(mx, __shfl_xor(mx, 8));
      const float mnew = fmaxf(mrun[q], mx);
      const float scale = __expf(mrun[q] - mnew);
      const float p0 = __expf(sc0[q] - mnew);
      const float p1 = __expf(sc1[q] - mnew);
      const bf16 ph0 = __float2bfloat16(p0);
      const bf16 ph1 = __float2bfloat16(p1);
      // denominator from the bf16-rounded P actually used in PV
      float rs = __bfloat162float(ph0) + __bfloat162float(ph1);
      rs += __shfl_xor(rs, 1); rs += __shfl_xor(rs, 2);
      rs += __shfl_xor(rs, 4); rs += __shfl_xor(rs, 8);
      lrun[q] = lrun[q] * scale + rs;
      mrun[q] = mnew;
      Ps[wid][lg * 4 + q][lr]      = ph0;
      Ps[wid][lg * 4 + q][16 + lr] = ph1;
#pragma unroll
      for (int dc = 0; dc < 16; dc++) O[dc][q] *= scale;
    }
    // cross-lane LDS visibility within the wave (in-order LDS + explicit wait)
    asm volatile("s_waitcnt lgkmcnt(0)" ::: "memory");
    __builtin_amdgcn_sched_barrier(0);
    bf16x8 pa = *reinterpret_cast<const bf16x8*>(&Ps[wid][lr][lg * 8]);
#pragma unroll
    for (int dc = 0; dc < 16; dc++) {
      bf16x8 vf = *reinterpret_cast<const bf16x8*>(&Vs[dc * 16 + lr][lg * 8]);
      O[dc] = __builtin_amdgcn_mfma_f32_16x16x32_bf16(pa, vf, O[dc], 0, 0, 0);
    }
  }

  float rl[4];
#pragma unroll
  for (int q = 0; q < 4; q++) rl[q] = 1.0f / lrun[q];
#pragma unroll
  for (int dc = 0; dc < 16; dc++) {
    const int cd = dc * 16 + lr;
#pragma unroll
    for (int q = 0; q < 4; q++) {
      const int row = q0 + lg * 4 + q;
      const float v = O[dc][q] * rl[q];
      if (cd < 64) {
        Hres[(size_t)(b * 2048 + row) * 512 + h * 64 + cd] = __float2bfloat16(v);
      } else {
        const int c = (cd - 64) >> 6, t = (cd - 64) & 63;
        Vres[((size_t)(b * 2048 + row) * 3 + c) * 512 + h * 64 + t] = __float2bfloat16(v);
      }
    }
  }
}

// ---------------------------------------------------------------- launch
extern "C" void kernel_launch(void* const* d_in, const int* in_sizes, int n_in,
                              void* d_out, int out_size, void* d_ws, size_t ws_size,
                              hipStream_t stream) {
  const float* H   = (const float*)d_in[0];
  const float* V   = (const float*)d_in[1];
  const float* Dm  = (const float*)d_in[2];
  const float* rbf = (const float*)d_in[3];
  const int*   mask= (const int*)d_in[4];
  const float* Wq  = (const float*)d_in[5];
  const float* bq  = (const float*)d_in[6];
  const float* Wk  = (const float*)d_in[7];
  const float* bk  = (const float*)d_in[8];
  const float* Wv  = (const float*)d_in[9];
  const float* bv  = (const float*)d_in[10];
  const float* Wvv = (const float*)d_in[11];
  const float* Wo  = (const float*)d_in[12];
  const float* bo  = (const float*)d_in[13];
  const float* Wvo = (const float*)d_in[14];

  char* ws = (char*)d_ws;
  bf16* Hbf  = (bf16*)(ws);                    // 8,388,608 B   (aliased by Hres after last read)
  bf16* Vbf  = (bf16*)(ws + 8388608);          // 25,165,824 B  (aliased by Vres after last read)
  bf16* Wall = (bf16*)(ws + 33554432);         // 6,291,456 B
  bf16* Qw   = (bf16*)(ws + 39845888);         // 33,554,432 B
  bf16* Kw   = (bf16*)(ws + 73400320);         // 33,554,432 B
  bf16* Vtw  = (bf16*)(ws + 106954752);        // 33,554,432 B  (end 140,509,184)
  bf16* Hres = Hbf;
  bf16* Vres = Vbf;
  bf16* Wqb  = Wall;
  bf16* Wkb  = Wall + 1048576;
  bf16* Wvb  = Wall + 2097152;
  bf16* Wvvb = Wall + 2359296;
  bf16* Wob  = Wall + 2621440;
  bf16* Wvob = Wall + 2883584;

  cvt_plain<<<4096, 256, 0, stream>>>(H, Hbf, 4194304);
  cvt_vperm<<<12288, 256, 0, stream>>>(V, Vbf);
  cvt_weights<<<3072, 256, 0, stream>>>(Wq, Wk, Wv, Wvv, Wo, Wvo, Wall);

  gemm_bt<0><<<dim3(16, 64), 256, 0, stream>>>(Hbf, Wqb, bq, Qw);
  gemm_bt<1><<<dim3(16, 64), 256, 0, stream>>>(Hbf, Wkb, bk, Kw);
  gemm_bt<2><<<dim3(4, 64), 256, 0, stream>>>(Hbf, Wvb, bv, Vtw);
  gemm_bt<3><<<dim3(4, 192), 256, 0, stream>>>(Vbf, Wvvb, nullptr, Vtw);

  attn_kernel<<<dim3(8, 16, 4), 512, 0, stream>>>(Qw, Kw, Vtw, Dm, rbf, mask, Hres, Vres);

  gemm_bt<4><<<dim3(4, 64), 256, 0, stream>>>(Hres, Wob, bo, d_out);
  gemm_bt<5><<<dim3(4, 192), 256, 0, stream>>>(Vres, Wvob, nullptr, (float*)d_out + 4194304);
}

// Round 2
// 749.681 us; speedup vs baseline: 1.2819x; 1.2819x over previous
//
#include <hip/hip_runtime.h>
#include <hip/hip_bf16.h>
#include <stdint.h>

typedef __hip_bfloat16 bf16;
typedef __attribute__((ext_vector_type(8))) short bf16x8;   // 8 bf16 = 4 VGPRs
typedef __attribute__((ext_vector_type(4))) float f32x4;

#define DEVI __device__ __forceinline__

static constexpr float FACTOR = 0.0625f;  // 0.5 / sqrt(64)

DEVI unsigned short bfbits(float x) {
  return __builtin_bit_cast(unsigned short, __float2bfloat16(x));
}

// ---------------------------------------------------------------- converts
__global__ void cvt_plain(const float* __restrict__ src, bf16* __restrict__ dst, int n) {
  int i = (blockIdx.x * 256 + threadIdx.x) * 4;
  if (i >= n) return;
  float4 v = *reinterpret_cast<const float4*>(src + i);
  union { unsigned short u[4]; uint64_t d; } t;
  t.u[0] = bfbits(v.x); t.u[1] = bfbits(v.y); t.u[2] = bfbits(v.z); t.u[3] = bfbits(v.w);
  *reinterpret_cast<uint64_t*>(dst + i) = t.d;
}

// V [B,N,3,512] f32  ->  Vbf [3][B*N][512] bf16
__global__ void cvt_vperm(const float* __restrict__ src, bf16* __restrict__ dst) {
  int g = blockIdx.x * 256 + threadIdx.x;
  int k4  = (g & 127) * 4;
  int rem = g >> 7;                                // (b*2048+n)*3 + c
  int c  = rem % 3;
  int bn = rem / 3;
  float4 v = *reinterpret_cast<const float4*>(src + (size_t)rem * 512 + k4);
  union { unsigned short u[4]; uint64_t d; } t;
  t.u[0] = bfbits(v.x); t.u[1] = bfbits(v.y); t.u[2] = bfbits(v.z); t.u[3] = bfbits(v.w);
  *reinterpret_cast<uint64_t*>(dst + ((size_t)c * 8192 + bn) * 512 + k4) = t.d;
}

__global__ void cvt_weights(const float* __restrict__ wq, const float* __restrict__ wk,
                            const float* __restrict__ wv, const float* __restrict__ wvv,
                            const float* __restrict__ wo, const float* __restrict__ wvo,
                            bf16* __restrict__ dst) {
  int blk = blockIdx.x;
  const float* s; int off;
  if      (blk < 1024) { s = wq  + blk * 1024;          off = 0       + blk * 1024; }
  else if (blk < 2048) { s = wk  + (blk - 1024) * 1024; off = 1048576 + (blk - 1024) * 1024; }
  else if (blk < 2304) { s = wv  + (blk - 2048) * 1024; off = 2097152 + (blk - 2048) * 1024; }
  else if (blk < 2560) { s = wvv + (blk - 2304) * 1024; off = 2359296 + (blk - 2304) * 1024; }
  else if (blk < 2816) { s = wo  + (blk - 2560) * 1024; off = 2621440 + (blk - 2560) * 1024; }
  else                 { s = wvo + (blk - 2816) * 1024; off = 2883584 + (blk - 2816) * 1024; }
  int i = threadIdx.x * 4;
  float4 v = *reinterpret_cast<const float4*>(s + i);
  union { unsigned short u[4]; uint64_t d; } t;
  t.u[0] = bfbits(v.x); t.u[1] = bfbits(v.y); t.u[2] = bfbits(v.z); t.u[3] = bfbits(v.w);
  *reinterpret_cast<uint64_t*>(dst + off + i) = t.d;
}

// Bc[b][n][m] = mask[b][m] ? rbf[b][n][m] + D[b][n][m] : -1e30   (f32, into d_out)
__global__ void bias_combine(const float* __restrict__ D, const float* __restrict__ rbf,
                             const int* __restrict__ mask, float* __restrict__ Bc) {
  size_t i = ((size_t)blockIdx.x * 256 + threadIdx.x) * 4;
  int col = (int)(i & 2047);
  int b   = (int)(i >> 22);
  float4 d = *reinterpret_cast<const float4*>(D + i);
  float4 r = *reinterpret_cast<const float4*>(rbf + i);
  const int* mrow = mask + b * 2048 + col;
  float4 o;
  o.x = mrow[0] ? d.x + r.x : -1e30f;
  o.y = mrow[1] ? d.y + r.y : -1e30f;
  o.z = mrow[2] ? d.z + r.z : -1e30f;
  o.w = mrow[3] ? d.w + r.w : -1e30f;
  *reinterpret_cast<float4*>(Bc + i) = o;
}

// ---------------------------------------------------------------- GEMM  C = A @ W^T (+bias)
template<int MODE>
__global__ __launch_bounds__(256, 2) void gemm_bt(const bf16* __restrict__ A,
                                                  const bf16* __restrict__ W,
                                                  const float* __restrict__ bias,
                                                  void* __restrict__ outp) {
  constexpr int K = 512;
  __shared__ bf16 As[128][40];
  __shared__ bf16 Bs[128][40];
  const int tid = threadIdx.x;
  const int wid = tid >> 6, lane = tid & 63;
  const int lr = lane & 15, lg = lane >> 4;
  const int wr = wid >> 1, wc = wid & 1;
  const int bm = blockIdx.y * 128, bn = blockIdx.x * 128;
  const int srow = tid >> 2;
  const int scol = (tid & 3) * 8;
  const bf16* Ap = A + (size_t)(bm + srow) * K + scol;
  const bf16* Wp = W + (size_t)(bn + srow) * K + scol;

  f32x4 acc[4][4];
#pragma unroll
  for (int m = 0; m < 4; m++)
#pragma unroll
    for (int n = 0; n < 4; n++) acc[m][n] = (f32x4){0.f, 0.f, 0.f, 0.f};

  bf16x8 a0 = *reinterpret_cast<const bf16x8*>(Ap);
  bf16x8 a1 = *reinterpret_cast<const bf16x8*>(Ap + 64 * K);
  bf16x8 b0 = *reinterpret_cast<const bf16x8*>(Wp);
  bf16x8 b1 = *reinterpret_cast<const bf16x8*>(Wp + 64 * K);

  for (int kt = 0; kt < 16; ++kt) {
    __syncthreads();
    *reinterpret_cast<bf16x8*>(&As[srow][scol])      = a0;
    *reinterpret_cast<bf16x8*>(&As[srow + 64][scol]) = a1;
    *reinterpret_cast<bf16x8*>(&Bs[srow][scol])      = b0;
    *reinterpret_cast<bf16x8*>(&Bs[srow + 64][scol]) = b1;
    __syncthreads();
    if (kt < 15) {
      a0 = *reinterpret_cast<const bf16x8*>(Ap + (kt + 1) * 32);
      a1 = *reinterpret_cast<const bf16x8*>(Ap + (kt + 1) * 32 + 64 * K);
      b0 = *reinterpret_cast<const bf16x8*>(Wp + (kt + 1) * 32);
      b1 = *reinterpret_cast<const bf16x8*>(Wp + (kt + 1) * 32 + 64 * K);
    }
    bf16x8 af[4], bfr[4];
#pragma unroll
    for (int m = 0; m < 4; m++)
      af[m] = *reinterpret_cast<const bf16x8*>(&As[wr * 64 + m * 16 + lr][lg * 8]);
#pragma unroll
    for (int n = 0; n < 4; n++)
      bfr[n] = *reinterpret_cast<const bf16x8*>(&Bs[wc * 64 + n * 16 + lr][lg * 8]);
#pragma unroll
    for (int m = 0; m < 4; m++)
#pragma unroll
      for (int n = 0; n < 4; n++)
        acc[m][n] = __builtin_amdgcn_mfma_f32_16x16x32_bf16(af[m], bfr[n], acc[m][n], 0, 0, 0);
  }

#pragma unroll
  for (int m = 0; m < 4; m++) {
#pragma unroll
    for (int n = 0; n < 4; n++) {
      const int col  = bn + wc * 64 + n * 16 + lr;
      const int row0 = bm + wr * 64 + m * 16 + lg * 4;
      if constexpr (MODE == 0 || MODE == 1) {
        bf16* out = (bf16*)outp;
        const float bb = bias[col];
        const int hh = col >> 8, t = col & 255;
#pragma unroll
        for (int q = 0; q < 4; q++) {
          const int row = row0 + q;
          const int b = row >> 11, nn = row & 2047;
          float v = acc[m][n][q] + bb;
          if constexpr (MODE == 0) v *= FACTOR;
          out[(size_t)((b * 8 + hh) * 2048 + nn) * 256 + t] = __float2bfloat16(v);
        }
      } else if constexpr (MODE == 2) {
        bf16* out = (bf16*)outp;
        const float bb = bias[col];
        const int hh = col >> 6, t = col & 63;
        const int b = row0 >> 11, nn = row0 & 2047;
        union { unsigned short u[4]; uint64_t d; } pk;
#pragma unroll
        for (int q = 0; q < 4; q++) pk.u[q] = bfbits(acc[m][n][q] + bb);
        *reinterpret_cast<uint64_t*>(out + ((size_t)((b * 8 + hh) * 256 + t)) * 2048 + nn) = pk.d;
      } else if constexpr (MODE == 3) {
        bf16* out = (bf16*)outp;
        const int hh = col >> 6, t = col & 63;
        const int c = row0 >> 13, b = (row0 >> 11) & 3, nn = row0 & 2047;
        union { unsigned short u[4]; uint64_t d; } pk;
#pragma unroll
        for (int q = 0; q < 4; q++) pk.u[q] = bfbits(acc[m][n][q]);
        *reinterpret_cast<uint64_t*>(out + ((size_t)((b * 8 + hh) * 256 + 64 + c * 64 + t)) * 2048 + nn) = pk.d;
      } else {
        float* out = (float*)outp;
        const float bb = (MODE == 4) ? bias[col] : 0.f;
#pragma unroll
        for (int q = 0; q < 4; q++) out[(size_t)(row0 + q) * 512 + col] = acc[m][n][q] + bb;
      }
    }
  }
}

// ---------------------------------------------------------------- flash attention
// grid (h=8, qt=16, b=4), block 512 (8 waves x 16 q-rows). Q prescaled by FACTOR.
// K/V double-buffered in LDS via global_load_lds; K XOR-swizzled (pre-swizzled source).
__global__ __launch_bounds__(512, 4) void attn_kernel(
    const bf16* __restrict__ Qg, const bf16* __restrict__ Kg, const bf16* __restrict__ Vtg,
    const float* __restrict__ Bc, bf16* __restrict__ Hres, bf16* __restrict__ Vres) {
  __shared__ bf16 Ks[2][32 * 256];   // [key][dim], 512B rows, byte ^= ((row&7)<<4)
  __shared__ bf16 Vs[2][256 * 32];   // [dim][key], 64B rows, linear
  __shared__ bf16 Ps[8][16][40];     // per-wave P^T staging [q][key]

  const int h = blockIdx.x, qt = blockIdx.y, b = blockIdx.z;
  const int bh = b * 8 + h;
  const int tid = threadIdx.x, wid = tid >> 6, lane = tid & 63;
  const int lr = lane & 15, lg = lane >> 4;
  const int q0 = qt * 128 + wid * 16;

  const bf16* Qb = Qg + (size_t)bh * 2048 * 256;
  const bf16* Kb = Kg + (size_t)bh * 2048 * 256;
  const bf16* Vb = Vtg + (size_t)bh * 256 * 2048;
  const float* Bb = Bc + (size_t)b * 2048 * 2048;

  bf16x8 qf[8];
#pragma unroll
  for (int kc = 0; kc < 8; kc++)
    qf[kc] = *reinterpret_cast<const bf16x8*>(Qb + (size_t)(q0 + lr) * 256 + kc * 32 + lg * 8);

  f32x4 O[16];
#pragma unroll
  for (int dc = 0; dc < 16; dc++) O[dc] = (f32x4){0.f, 0.f, 0.f, 0.f};
  float mrun[4], lrun[4];
#pragma unroll
  for (int q = 0; q < 4; q++) { mrun[q] = -INFINITY; lrun[q] = 0.f; }

  // global_load_lds source addresses (per wave: 2 instrs each for K and V)
  const int d0 = wid * 2048 + lane * 16;
  const int d1 = d0 + 1024;
  const int kr0 = d0 >> 9, kc0 = d0 & 511;
  const int kr1 = d1 >> 9, kc1 = d1 & 511;
  const char* ksrc0 = (const char*)Kb + (size_t)kr0 * 512 + (kc0 ^ ((kr0 & 7) << 4));
  const char* ksrc1 = (const char*)Kb + (size_t)kr1 * 512 + (kc1 ^ ((kr1 & 7) << 4));
  const char* vsrc0 = (const char*)Vb + (size_t)(d0 >> 6) * 4096 + (d0 & 63);
  const char* vsrc1 = (const char*)Vb + (size_t)(d1 >> 6) * 4096 + (d1 & 63);
  const int wofs = wid * 2048;   // byte offset into each tile buffer

  const float* Bbase = Bb + (size_t)(q0 + lg * 4) * 2048 + lr;

  // prologue: stage tile 0 into buf 0
  {
    char* ldsK = (char*)&Ks[0][0] + wofs;
    char* ldsV = (char*)&Vs[0][0] + wofs;
    __builtin_amdgcn_global_load_lds(ksrc0, ldsK, 16, 0, 0);
    __builtin_amdgcn_global_load_lds(ksrc1, ldsK + 1024, 16, 0, 0);
    __builtin_amdgcn_global_load_lds(vsrc0, ldsV, 16, 0, 0);
    __builtin_amdgcn_global_load_lds(vsrc1, ldsV + 1024, 16, 0, 0);
    ksrc0 += 16384; ksrc1 += 16384; vsrc0 += 64; vsrc1 += 64;
  }
  __syncthreads();

  for (int kt = 0; kt < 64; ++kt) {
    const int cur = kt & 1;
    // bias loads for CURRENT tile (issued first so consuming them leaves stage loads in flight)
    const float* bp = Bbase + kt * 32;
    float b0 = bp[0],    b1 = bp[16];
    float b2 = bp[2048], b3 = bp[2064];
    float b4 = bp[4096], b5 = bp[4112];
    float b6 = bp[6144], b7 = bp[6160];
    // stage NEXT tile into the other buffer
    if (kt < 63) {
      char* ldsK = (char*)&Ks[cur ^ 1][0] + wofs;
      char* ldsV = (char*)&Vs[cur ^ 1][0] + wofs;
      __builtin_amdgcn_global_load_lds(ksrc0, ldsK, 16, 0, 0);
      __builtin_amdgcn_global_load_lds(ksrc1, ldsK + 1024, 16, 0, 0);
      __builtin_amdgcn_global_load_lds(vsrc0, ldsV, 16, 0, 0);
      __builtin_amdgcn_global_load_lds(vsrc1, ldsV + 1024, 16, 0, 0);
      ksrc0 += 16384; ksrc1 += 16384; vsrc0 += 64; vsrc1 += 64;
    }

    // S = Q @ K^T  (swizzled K reads: conflict-free)
    const char* KsC = (const char*)&Ks[cur][0];
    f32x4 s0 = (f32x4){0.f, 0.f, 0.f, 0.f}, s1 = (f32x4){0.f, 0.f, 0.f, 0.f};
#pragma unroll
    for (int kc = 0; kc < 8; kc++) {
      const int cb = (kc * 64 + lg * 16) ^ ((lr & 7) << 4);
      bf16x8 k0f = *reinterpret_cast<const bf16x8*>(KsC + lr * 512 + cb);
      bf16x8 k1f = *reinterpret_cast<const bf16x8*>(KsC + (16 + lr) * 512 + cb);
      s0 = __builtin_amdgcn_mfma_f32_16x16x32_bf16(qf[kc], k0f, s0, 0, 0, 0);
      s1 = __builtin_amdgcn_mfma_f32_16x16x32_bf16(qf[kc], k1f, s1, 0, 0, 0);
    }
    // add bias
    s0[0] += b0; s1[0] += b1;
    s0[1] += b2; s1[1] += b3;
    s0[2] += b4; s1[2] += b5;
    s0[3] += b6; s1[3] += b7;

    // row max (16-lane reduce per q)
    float mx[4];
#pragma unroll
    for (int q = 0; q < 4; q++) {
      float m = fmaxf(s0[q], s1[q]);
      m = fmaxf(m, __shfl_xor(m, 1));
      m = fmaxf(m, __shfl_xor(m, 2));
      m = fmaxf(m, __shfl_xor(m, 4));
      m = fmaxf(m, __shfl_xor(m, 8));
      mx[q] = m;
    }
    // defer-max: rescale only when some row's max grew by > 8
    bool ok = (mx[0] <= mrun[0] + 8.f) && (mx[1] <= mrun[1] + 8.f) &&
              (mx[2] <= mrun[2] + 8.f) && (mx[3] <= mrun[3] + 8.f);
    if (!__all((int)ok)) {
#pragma unroll
      for (int q = 0; q < 4; q++) {
        const float mnew = fmaxf(mrun[q], mx[q]);
        const float sc = __expf(mrun[q] - mnew);
        lrun[q] *= sc;
        mrun[q] = mnew;
#pragma unroll
        for (int dc = 0; dc < 16; dc++) O[dc][q] *= sc;
      }
    }
#pragma unroll
    for (int q = 0; q < 4; q++) {
      const float p0 = __expf(s0[q] - mrun[q]);
      const float p1 = __expf(s1[q] - mrun[q]);
      const bf16 ph0 = __float2bfloat16(p0);
      const bf16 ph1 = __float2bfloat16(p1);
      float rs = __bfloat162float(ph0) + __bfloat162float(ph1);
      rs += __shfl_xor(rs, 1); rs += __shfl_xor(rs, 2);
      rs += __shfl_xor(rs, 4); rs += __shfl_xor(rs, 8);
      lrun[q] += rs;
      Ps[wid][lg * 4 + q][lr]      = ph0;
      Ps[wid][lg * 4 + q][16 + lr] = ph1;
    }
    asm volatile("s_waitcnt lgkmcnt(0)" ::: "memory");
    __builtin_amdgcn_sched_barrier(0);
    bf16x8 pa = *reinterpret_cast<const bf16x8*>(&Ps[wid][lr][lg * 8]);
    const bf16* VsC = &Vs[cur][0];
#pragma unroll
    for (int dc = 0; dc < 16; dc++) {
      bf16x8 vf = *reinterpret_cast<const bf16x8*>(VsC + (dc * 16 + lr) * 32 + lg * 8);
      O[dc] = __builtin_amdgcn_mfma_f32_16x16x32_bf16(pa, vf, O[dc], 0, 0, 0);
    }
    __syncthreads();   // compiler drains vmcnt(0): next tile fully staged
  }

  float rl[4];
#pragma unroll
  for (int q = 0; q < 4; q++) rl[q] = 1.0f / lrun[q];
#pragma unroll
  for (int dc = 0; dc < 16; dc++) {
    const int cd = dc * 16 + lr;
#pragma unroll
    for (int q = 0; q < 4; q++) {
      const int row = q0 + lg * 4 + q;
      const float v = O[dc][q] * rl[q];
      if (cd < 64) {
        Hres[(size_t)(b * 2048 + row) * 512 + h * 64 + cd] = __float2bfloat16(v);
      } else {
        const int c = (cd - 64) >> 6, t = (cd - 64) & 63;
        Vres[((size_t)(b * 2048 + row) * 3 + c) * 512 + h * 64 + t] = __float2bfloat16(v);
      }
    }
  }
}

// ---------------------------------------------------------------- launch
extern "C" void kernel_launch(void* const* d_in, const int* in_sizes, int n_in,
                              void* d_out, int out_size, void* d_ws, size_t ws_size,
                              hipStream_t stream) {
  const float* H   = (const float*)d_in[0];
  const float* V   = (const float*)d_in[1];
  const float* Dm  = (const float*)d_in[2];
  const float* rbf = (const float*)d_in[3];
  const int*   mask= (const int*)d_in[4];
  const float* Wq  = (const float*)d_in[5];
  const float* bq  = (const float*)d_in[6];
  const float* Wk  = (const float*)d_in[7];
  const float* bk  = (const float*)d_in[8];
  const float* Wv  = (const float*)d_in[9];
  const float* bv  = (const float*)d_in[10];
  const float* Wvv = (const float*)d_in[11];
  const float* Wo  = (const float*)d_in[12];
  const float* bo  = (const float*)d_in[13];
  const float* Wvo = (const float*)d_in[14];

  char* ws = (char*)d_ws;
  bf16* Hbf  = (bf16*)(ws);                    // aliased by Hres after last read
  bf16* Vbf  = (bf16*)(ws + 8388608);          // aliased by Vres after last read
  bf16* Wall = (bf16*)(ws + 33554432);
  bf16* Qw   = (bf16*)(ws + 39845888);
  bf16* Kw   = (bf16*)(ws + 73400320);
  bf16* Vtw  = (bf16*)(ws + 106954752);
  bf16* Hres = Hbf;
  bf16* Vres = Vbf;
  bf16* Wqb  = Wall;
  bf16* Wkb  = Wall + 1048576;
  bf16* Wvb  = Wall + 2097152;
  bf16* Wvvb = Wall + 2359296;
  bf16* Wob  = Wall + 2621440;
  bf16* Wvob = Wall + 2883584;
  float* Bc  = (float*)d_out;                  // 16,777,216 f32 == out_size, read fully by attn
                                               // before final GEMMs overwrite d_out

  bias_combine<<<16384, 256, 0, stream>>>(Dm, rbf, mask, Bc);
  cvt_plain<<<4096, 256, 0, stream>>>(H, Hbf, 4194304);
  cvt_vperm<<<12288, 256, 0, stream>>>(V, Vbf);
  cvt_weights<<<3072, 256, 0, stream>>>(Wq, Wk, Wv, Wvv, Wo, Wvo, Wall);

  gemm_bt<0><<<dim3(16, 64), 256, 0, stream>>>(Hbf, Wqb, bq, Qw);
  gemm_bt<1><<<dim3(16, 64), 256, 0, stream>>>(Hbf, Wkb, bk, Kw);
  gemm_bt<2><<<dim3(4, 64), 256, 0, stream>>>(Hbf, Wvb, bv, Vtw);
  gemm_bt<3><<<dim3(4, 192), 256, 0, stream>>>(Vbf, Wvvb, nullptr, Vtw);

  attn_kernel<<<dim3(8, 16, 4), 512, 0, stream>>>(Qw, Kw, Vtw, Bc, Hres, Vres);

  gemm_bt<4><<<dim3(4, 64), 256, 0, stream>>>(Hres, Wob, bo, d_out);
  gemm_bt<5><<<dim3(4, 192), 256, 0, stream>>>(Vres, Wvob, nullptr, (float*)d_out + 4194304);
}

// Round 3
// 592.210 us; speedup vs baseline: 1.6228x; 1.2659x over previous
//
#include <hip/hip_runtime.h>
#include <hip/hip_bf16.h>
#include <stdint.h>

typedef __hip_bfloat16 bf16;
typedef __attribute__((ext_vector_type(8))) short bf16x8;   // 8 bf16 = 4 VGPRs
typedef __attribute__((ext_vector_type(4))) float f32x4;

#define DEVI __device__ __forceinline__

static constexpr float FACTOR = 0.0625f;  // 0.5 / sqrt(64)

DEVI unsigned short bfbits(float x) {
  return __builtin_bit_cast(unsigned short, __float2bfloat16(x));
}

// ---------------------------------------------------------------- converts
__global__ void cvt_plain(const float* __restrict__ src, bf16* __restrict__ dst, int n) {
  int i = (blockIdx.x * 256 + threadIdx.x) * 4;
  if (i >= n) return;
  float4 v = *reinterpret_cast<const float4*>(src + i);
  union { unsigned short u[4]; uint64_t d; } t;
  t.u[0] = bfbits(v.x); t.u[1] = bfbits(v.y); t.u[2] = bfbits(v.z); t.u[3] = bfbits(v.w);
  *reinterpret_cast<uint64_t*>(dst + i) = t.d;
}

// V [B,N,3,512] f32  ->  Vbf [3][B*N][512] bf16
__global__ void cvt_vperm(const float* __restrict__ src, bf16* __restrict__ dst) {
  int g = blockIdx.x * 256 + threadIdx.x;
  int k4  = (g & 127) * 4;
  int rem = g >> 7;                                // (b*2048+n)*3 + c
  int c  = rem % 3;
  int bn = rem / 3;
  float4 v = *reinterpret_cast<const float4*>(src + (size_t)rem * 512 + k4);
  union { unsigned short u[4]; uint64_t d; } t;
  t.u[0] = bfbits(v.x); t.u[1] = bfbits(v.y); t.u[2] = bfbits(v.z); t.u[3] = bfbits(v.w);
  *reinterpret_cast<uint64_t*>(dst + ((size_t)c * 8192 + bn) * 512 + k4) = t.d;
}

__global__ void cvt_weights(const float* __restrict__ wq, const float* __restrict__ wk,
                            const float* __restrict__ wv, const float* __restrict__ wvv,
                            const float* __restrict__ wo, const float* __restrict__ wvo,
                            bf16* __restrict__ dst) {
  int blk = blockIdx.x;
  const float* s; int off;
  if      (blk < 1024) { s = wq  + blk * 1024;          off = 0       + blk * 1024; }
  else if (blk < 2048) { s = wk  + (blk - 1024) * 1024; off = 1048576 + (blk - 1024) * 1024; }
  else if (blk < 2304) { s = wv  + (blk - 2048) * 1024; off = 2097152 + (blk - 2048) * 1024; }
  else if (blk < 2560) { s = wvv + (blk - 2304) * 1024; off = 2359296 + (blk - 2304) * 1024; }
  else if (blk < 2816) { s = wo  + (blk - 2560) * 1024; off = 2621440 + (blk - 2560) * 1024; }
  else                 { s = wvo + (blk - 2816) * 1024; off = 2883584 + (blk - 2816) * 1024; }
  int i = threadIdx.x * 4;
  float4 v = *reinterpret_cast<const float4*>(s + i);
  union { unsigned short u[4]; uint64_t d; } t;
  t.u[0] = bfbits(v.x); t.u[1] = bfbits(v.y); t.u[2] = bfbits(v.z); t.u[3] = bfbits(v.w);
  *reinterpret_cast<uint64_t*>(dst + off + i) = t.d;
}

// Bc[b][n][m] = mask[b][m] ? rbf[b][n][m] + D[b][n][m] : -1e30   (f32, into d_out)
__global__ void bias_combine(const float* __restrict__ D, const float* __restrict__ rbf,
                             const int* __restrict__ mask, float* __restrict__ Bc) {
  size_t i = ((size_t)blockIdx.x * 256 + threadIdx.x) * 4;
  int col = (int)(i & 2047);
  int b   = (int)(i >> 22);
  float4 d = *reinterpret_cast<const float4*>(D + i);
  float4 r = *reinterpret_cast<const float4*>(rbf + i);
  const int* mrow = mask + b * 2048 + col;
  float4 o;
  o.x = mrow[0] ? d.x + r.x : -1e30f;
  o.y = mrow[1] ? d.y + r.y : -1e30f;
  o.z = mrow[2] ? d.z + r.z : -1e30f;
  o.w = mrow[3] ? d.w + r.w : -1e30f;
  *reinterpret_cast<float4*>(Bc + i) = o;
}

// ---------------------------------------------------------------- GEMM  C = A @ W^T (+bias)
// MODE 0: -> Q [b,h,n,256] bf16, (acc+bq)*FACTOR      MODE 1: -> K same layout, +bk
// MODE 2: Hv -> Vt[(bh*256+t)*2048 + perm(n)], +bv    MODE 3: Vv -> Vt[.. +64+c*64+t .. perm(n)]
//   (tau key-permutation within each 32-key tile: chunk i -> chunk ((i&3)<<1)|(i>>2))
// MODE 4: -> d_out f32 (+bo)                          MODE 5: -> d_out+4194304 f32
template<int MODE>
__global__ __launch_bounds__(256, 2) void gemm_bt(const bf16* __restrict__ A,
                                                  const bf16* __restrict__ W,
                                                  const float* __restrict__ bias,
                                                  void* __restrict__ outp) {
  constexpr int K = 512;
  __shared__ bf16 As[128][40];
  __shared__ bf16 Bs[128][40];
  const int tid = threadIdx.x;
  const int wid = tid >> 6, lane = tid & 63;
  const int lr = lane & 15, lg = lane >> 4;
  const int wr = wid >> 1, wc = wid & 1;
  const int bm = blockIdx.y * 128, bn = blockIdx.x * 128;
  const int srow = tid >> 2;
  const int scol = (tid & 3) * 8;
  const bf16* Ap = A + (size_t)(bm + srow) * K + scol;
  const bf16* Wp = W + (size_t)(bn + srow) * K + scol;

  f32x4 acc[4][4];
#pragma unroll
  for (int m = 0; m < 4; m++)
#pragma unroll
    for (int n = 0; n < 4; n++) acc[m][n] = (f32x4){0.f, 0.f, 0.f, 0.f};

  bf16x8 a0 = *reinterpret_cast<const bf16x8*>(Ap);
  bf16x8 a1 = *reinterpret_cast<const bf16x8*>(Ap + 64 * K);
  bf16x8 b0 = *reinterpret_cast<const bf16x8*>(Wp);
  bf16x8 b1 = *reinterpret_cast<const bf16x8*>(Wp + 64 * K);

  for (int kt = 0; kt < 16; ++kt) {
    __syncthreads();
    *reinterpret_cast<bf16x8*>(&As[srow][scol])      = a0;
    *reinterpret_cast<bf16x8*>(&As[srow + 64][scol]) = a1;
    *reinterpret_cast<bf16x8*>(&Bs[srow][scol])      = b0;
    *reinterpret_cast<bf16x8*>(&Bs[srow + 64][scol]) = b1;
    __syncthreads();
    if (kt < 15) {
      a0 = *reinterpret_cast<const bf16x8*>(Ap + (kt + 1) * 32);
      a1 = *reinterpret_cast<const bf16x8*>(Ap + (kt + 1) * 32 + 64 * K);
      b0 = *reinterpret_cast<const bf16x8*>(Wp + (kt + 1) * 32);
      b1 = *reinterpret_cast<const bf16x8*>(Wp + (kt + 1) * 32 + 64 * K);
    }
    bf16x8 af[4], bfr[4];
#pragma unroll
    for (int m = 0; m < 4; m++)
      af[m] = *reinterpret_cast<const bf16x8*>(&As[wr * 64 + m * 16 + lr][lg * 8]);
#pragma unroll
    for (int n = 0; n < 4; n++)
      bfr[n] = *reinterpret_cast<const bf16x8*>(&Bs[wc * 64 + n * 16 + lr][lg * 8]);
#pragma unroll
    for (int m = 0; m < 4; m++)
#pragma unroll
      for (int n = 0; n < 4; n++)
        acc[m][n] = __builtin_amdgcn_mfma_f32_16x16x32_bf16(af[m], bfr[n], acc[m][n], 0, 0, 0);
  }

#pragma unroll
  for (int m = 0; m < 4; m++) {
#pragma unroll
    for (int n = 0; n < 4; n++) {
      const int col  = bn + wc * 64 + n * 16 + lr;
      const int row0 = bm + wr * 64 + m * 16 + lg * 4;
      if constexpr (MODE == 0 || MODE == 1) {
        bf16* out = (bf16*)outp;
        const float bb = bias[col];
        const int hh = col >> 8, t = col & 255;
#pragma unroll
        for (int q = 0; q < 4; q++) {
          const int row = row0 + q;
          const int b = row >> 11, nn = row & 2047;
          float v = acc[m][n][q] + bb;
          if constexpr (MODE == 0) v *= FACTOR;
          out[(size_t)((b * 8 + hh) * 2048 + nn) * 256 + t] = __float2bfloat16(v);
        }
      } else if constexpr (MODE == 2 || MODE == 3) {
        bf16* out = (bf16*)outp;
        const int hh = col >> 6, t = col & 63;
        int dimrow, b, nn;
        if constexpr (MODE == 2) {
          b = row0 >> 11; nn = row0 & 2047;
          dimrow = (b * 8 + hh) * 256 + t;
        } else {
          const int c = row0 >> 13; b = (row0 >> 11) & 3; nn = row0 & 2047;
          dimrow = (b * 8 + hh) * 256 + 64 + c * 64 + t;
        }
        // tau key-permutation: 4-key chunk i -> chunk ((i&3)<<1)|(i>>2) within 32-key tile
        const int i4 = (nn >> 2) & 7;
        const int o4 = ((i4 & 3) << 1) | (i4 >> 2);
        const int nn2 = (nn & ~31) | (o4 << 2);
        const float bb = (MODE == 2) ? bias[col] : 0.f;
        union { unsigned short u[4]; uint64_t d; } pk;
#pragma unroll
        for (int q = 0; q < 4; q++) pk.u[q] = bfbits(acc[m][n][q] + bb);
        *reinterpret_cast<uint64_t*>(out + (size_t)dimrow * 2048 + nn2) = pk.d;
      } else {
        float* out = (float*)outp;
        const float bb = (MODE == 4) ? bias[col] : 0.f;
#pragma unroll
        for (int q = 0; q < 4; q++) out[(size_t)(row0 + q) * 512 + col] = acc[m][n][q] + bb;
      }
    }
  }
}

// ---------------------------------------------------------------- flash attention
// 1-D grid 512, block 512 (8 waves x 16 q-rows). Swapped QK^T: S^T = mfma(K,Q).
// XCD mapping: xcd = g&7 owns (b = xcd>>1, 8 consecutive qt, all 8 h) -> K/V + bias L2 reuse.
__global__ __launch_bounds__(512, 4) void attn_kernel(
    const bf16* __restrict__ Qg, const bf16* __restrict__ Kg, const bf16* __restrict__ Vtg,
    const float* __restrict__ Bc, bf16* __restrict__ Hres, bf16* __restrict__ Vres) {
  __shared__ bf16 Ks[2][32 * 256];   // [key][dim] 512B rows, byte ^= ((row&7)<<4)
  __shared__ bf16 Vs[2][256 * 32];   // [dim][key] 64B rows, 16B-block col ^= ((row>>1)&3), tau keys

  const int g = blockIdx.x;
  const int xcd = g & 7, lo = g >> 3;
  const int h = lo >> 3;
  const int b = xcd >> 1;
  const int qt = ((xcd & 1) << 3) | (lo & 7);
  const int bh = b * 8 + h;
  const int tid = threadIdx.x, wid = tid >> 6, lane = tid & 63;
  const int lr = lane & 15, lg = lane >> 4;
  const int q0 = qt * 128 + wid * 16;

  const bf16* Qb = Qg + (size_t)bh * 2048 * 256;
  const bf16* Kb = Kg + (size_t)bh * 2048 * 256;
  const bf16* Vb = Vtg + (size_t)bh * 256 * 2048;
  const float* Bb = Bc + (size_t)b * 2048 * 2048;

  bf16x8 qf[8];
#pragma unroll
  for (int kc = 0; kc < 8; kc++)
    qf[kc] = *reinterpret_cast<const bf16x8*>(Qb + (size_t)(q0 + lr) * 256 + kc * 32 + lg * 8);

  f32x4 O[16];
#pragma unroll
  for (int dc = 0; dc < 16; dc++) O[dc] = (f32x4){0.f, 0.f, 0.f, 0.f};
  float mrun = -INFINITY, lrun = 0.f;   // per-lane state for q-row = q0 + lr

  // staging: per-thread LDS dest X = wid*2048 + lane*16 (implicit lane*16 in gload_lds)
  const int d0 = wid * 2048 + lane * 16;
  const int kr0 = d0 >> 9, kc0 = d0 & 511;
  const int kr1 = (d0 + 1024) >> 9, kc1 = (d0 + 1024) & 511;
  const char* ksrc0 = (const char*)Kb + (size_t)kr0 * 512 + (kc0 ^ ((kr0 & 7) << 4));
  const char* ksrc1 = (const char*)Kb + (size_t)kr1 * 512 + (kc1 ^ ((kr1 & 7) << 4));
  const int vr0 = d0 >> 6;                         // dim row
  const int vblk_s = (lane & 3) ^ ((lane >> 3) & 3);
  const char* vsrc0 = (const char*)Vb + (size_t)vr0 * 4096 + (vblk_s << 4);
  const char* vsrc1 = vsrc0 + 16 * 4096;
  const int wofs = wid * 2048;

  // PV read column block (dc-independent): slot-distinct XOR
  const int vblk_r = (lg ^ ((lr >> 1) & 3)) << 4;

  // prologue: stage tile 0 into buf 0
  {
    char* ldsK = (char*)&Ks[0][0] + wofs;
    char* ldsV = (char*)&Vs[0][0] + wofs;
    __builtin_amdgcn_global_load_lds(ksrc0, ldsK, 16, 0, 0);
    __builtin_amdgcn_global_load_lds(ksrc1, ldsK + 1024, 16, 0, 0);
    __builtin_amdgcn_global_load_lds(vsrc0, ldsV, 16, 0, 0);
    __builtin_amdgcn_global_load_lds(vsrc1, ldsV + 1024, 16, 0, 0);
    ksrc0 += 16384; ksrc1 += 16384; vsrc0 += 64; vsrc1 += 64;
  }
  __syncthreads();

  const float* Bbase = Bb + (size_t)(q0 + lr) * 2048 + lg * 4;

  for (int kt = 0; kt < 64; ++kt) {
    const int cur = kt & 1;
    // bias for current tile: scores S^T[key=kt*32+lg*4+r(+16)][q=q0+lr]
    float4 ba = *reinterpret_cast<const float4*>(Bbase + kt * 32);
    float4 bb = *reinterpret_cast<const float4*>(Bbase + kt * 32 + 16);
    // stage next tile
    if (kt < 63) {
      char* ldsK = (char*)&Ks[cur ^ 1][0] + wofs;
      char* ldsV = (char*)&Vs[cur ^ 1][0] + wofs;
      __builtin_amdgcn_global_load_lds(ksrc0, ldsK, 16, 0, 0);
      __builtin_amdgcn_global_load_lds(ksrc1, ldsK + 1024, 16, 0, 0);
      __builtin_amdgcn_global_load_lds(vsrc0, ldsV, 16, 0, 0);
      __builtin_amdgcn_global_load_lds(vsrc1, ldsV + 1024, 16, 0, 0);
      ksrc0 += 16384; ksrc1 += 16384; vsrc0 += 64; vsrc1 += 64;
    }

    // S^T = K @ Q^T : A = K-frag (rows=key), B = Q-frag (cols=q)
    const char* KsC = (const char*)&Ks[cur][0];
    f32x4 s_a = (f32x4){0.f, 0.f, 0.f, 0.f}, s_b = (f32x4){0.f, 0.f, 0.f, 0.f};
#pragma unroll
    for (int kc = 0; kc < 8; kc++) {
      const int cb = (kc * 64 + lg * 16) ^ ((lr & 7) << 4);
      bf16x8 k0f = *reinterpret_cast<const bf16x8*>(KsC + lr * 512 + cb);
      bf16x8 k1f = *reinterpret_cast<const bf16x8*>(KsC + (16 + lr) * 512 + cb);
      s_a = __builtin_amdgcn_mfma_f32_16x16x32_bf16(k0f, qf[kc], s_a, 0, 0, 0);
      s_b = __builtin_amdgcn_mfma_f32_16x16x32_bf16(k1f, qf[kc], s_b, 0, 0, 0);
    }
    // scores for 8 keys of q-row q0+lr, all lane-local
    float sc[8];
    sc[0] = s_a[0] + ba.x; sc[1] = s_a[1] + ba.y; sc[2] = s_a[2] + ba.z; sc[3] = s_a[3] + ba.w;
    sc[4] = s_b[0] + bb.x; sc[5] = s_b[1] + bb.y; sc[6] = s_b[2] + bb.z; sc[7] = s_b[3] + bb.w;

    // row max: in-lane 8 + xor16 + xor32 (lanes lr,lr+16,lr+32,lr+48 hold same q-row)
    float pmax = fmaxf(fmaxf(fmaxf(sc[0], sc[1]), fmaxf(sc[2], sc[3])),
                       fmaxf(fmaxf(sc[4], sc[5]), fmaxf(sc[6], sc[7])));
    pmax = fmaxf(pmax, __shfl_xor(pmax, 16));
    pmax = fmaxf(pmax, __shfl_xor(pmax, 32));

    // defer-max (THR=8)
    const bool ok = (pmax <= mrun + 8.f);
    if (!__all((int)ok)) {
      const float mnew = fmaxf(mrun, pmax);
      const float scq = __expf(mrun - mnew);
      lrun *= scq;
      mrun = mnew;
      float so[4];
#pragma unroll
      for (int r = 0; r < 4; r++) so[r] = __shfl(scq, lg * 4 + r);
#pragma unroll
      for (int dc = 0; dc < 16; dc++) {
#pragma unroll
        for (int r = 0; r < 4; r++) O[dc][r] *= so[r];
      }
    }

    // exp + pack PA fragment (tau ordering makes register order == A-frag order)
    union { unsigned short u[8]; bf16x8 v; } pk;
    float rs = 0.f;
#pragma unroll
    for (int j = 0; j < 8; j++) {
      const float p = __expf(sc[j] - mrun);
      const bf16 ph = __float2bfloat16(p);
      pk.u[j] = __builtin_bit_cast(unsigned short, ph);
      rs += __bfloat162float(ph);
    }
    rs += __shfl_xor(rs, 16);
    rs += __shfl_xor(rs, 32);
    lrun += rs;

    // PV: O[q][dim] += P @ V ; vf rows = dim, contraction = tau-ordered keys
    const char* VsC = (const char*)&Vs[cur][0];
#pragma unroll
    for (int dc = 0; dc < 16; dc++) {
      bf16x8 vf = *reinterpret_cast<const bf16x8*>(VsC + (dc * 16 + lr) * 64 + vblk_r);
      O[dc] = __builtin_amdgcn_mfma_f32_16x16x32_bf16(pk.v, vf, O[dc], 0, 0, 0);
    }
    __syncthreads();   // next tile staged (compiler drains vmcnt), old buffer reads done
  }

  // epilogue: O lane (lr,lg) holds dims dc*16+lr, q-rows q0+lg*4+r
  const float rli = 1.0f / lrun;
  float rl[4];
#pragma unroll
  for (int r = 0; r < 4; r++) rl[r] = __shfl(rli, lg * 4 + r);
#pragma unroll
  for (int dc = 0; dc < 16; dc++) {
    const int cd = dc * 16 + lr;
#pragma unroll
    for (int r = 0; r < 4; r++) {
      const int row = q0 + lg * 4 + r;
      const float v = O[dc][r] * rl[r];
      if (cd < 64) {
        Hres[(size_t)(b * 2048 + row) * 512 + h * 64 + cd] = __float2bfloat16(v);
      } else {
        const int c = (cd - 64) >> 6, t = (cd - 64) & 63;
        Vres[((size_t)(b * 2048 + row) * 3 + c) * 512 + h * 64 + t] = __float2bfloat16(v);
      }
    }
  }
}

// ---------------------------------------------------------------- launch
extern "C" void kernel_launch(void* const* d_in, const int* in_sizes, int n_in,
                              void* d_out, int out_size, void* d_ws, size_t ws_size,
                              hipStream_t stream) {
  const float* H   = (const float*)d_in[0];
  const float* V   = (const float*)d_in[1];
  const float* Dm  = (const float*)d_in[2];
  const float* rbf = (const float*)d_in[3];
  const int*   mask= (const int*)d_in[4];
  const float* Wq  = (const float*)d_in[5];
  const float* bq  = (const float*)d_in[6];
  const float* Wk  = (const float*)d_in[7];
  const float* bk  = (const float*)d_in[8];
  const float* Wv  = (const float*)d_in[9];
  const float* bv  = (const float*)d_in[10];
  const float* Wvv = (const float*)d_in[11];
  const float* Wo  = (const float*)d_in[12];
  const float* bo  = (const float*)d_in[13];
  const float* Wvo = (const float*)d_in[14];

  char* ws = (char*)d_ws;
  bf16* Hbf  = (bf16*)(ws);                    // aliased by Hres after last read
  bf16* Vbf  = (bf16*)(ws + 8388608);          // aliased by Vres after last read
  bf16* Wall = (bf16*)(ws + 33554432);
  bf16* Qw   = (bf16*)(ws + 39845888);
  bf16* Kw   = (bf16*)(ws + 73400320);
  bf16* Vtw  = (bf16*)(ws + 106954752);
  bf16* Hres = Hbf;
  bf16* Vres = Vbf;
  bf16* Wqb  = Wall;
  bf16* Wkb  = Wall + 1048576;
  bf16* Wvb  = Wall + 2097152;
  bf16* Wvvb = Wall + 2359296;
  bf16* Wob  = Wall + 2621440;
  bf16* Wvob = Wall + 2883584;
  float* Bc  = (float*)d_out;                  // read fully by attn before final GEMMs overwrite

  bias_combine<<<16384, 256, 0, stream>>>(Dm, rbf, mask, Bc);
  cvt_plain<<<4096, 256, 0, stream>>>(H, Hbf, 4194304);
  cvt_vperm<<<12288, 256, 0, stream>>>(V, Vbf);
  cvt_weights<<<3072, 256, 0, stream>>>(Wq, Wk, Wv, Wvv, Wo, Wvo, Wall);

  gemm_bt<0><<<dim3(16, 64), 256, 0, stream>>>(Hbf, Wqb, bq, Qw);
  gemm_bt<1><<<dim3(16, 64), 256, 0, stream>>>(Hbf, Wkb, bk, Kw);
  gemm_bt<2><<<dim3(4, 64), 256, 0, stream>>>(Hbf, Wvb, bv, Vtw);
  gemm_bt<3><<<dim3(4, 192), 256, 0, stream>>>(Vbf, Wvvb, nullptr, Vtw);

  attn_kernel<<<512, 512, 0, stream>>>(Qw, Kw, Vtw, Bc, Hres, Vres);

  gemm_bt<4><<<dim3(4, 64), 256, 0, stream>>>(Hres, Wob, bo, d_out);
  gemm_bt<5><<<dim3(4, 192), 256, 0, stream>>>(Vres, Wvob, nullptr, (float*)d_out + 4194304);
}

// Round 4
// 565.489 us; speedup vs baseline: 1.6994x; 1.0473x over previous
//
#include <hip/hip_runtime.h>
#include <hip/hip_bf16.h>
#include <stdint.h>

typedef __hip_bfloat16 bf16;
typedef __attribute__((ext_vector_type(8))) short bf16x8;   // 8 bf16 = 4 VGPRs
typedef __attribute__((ext_vector_type(4))) float f32x4;
typedef __attribute__((ext_vector_type(4))) unsigned short u16x4;

#define DEVI __device__ __forceinline__

static constexpr float FACTOR = 0.0625f;  // 0.5 / sqrt(64)

DEVI unsigned short bfbits(float x) {
  return __builtin_bit_cast(unsigned short, __float2bfloat16(x));
}
DEVI float b2f(unsigned short u) {
  return __builtin_bit_cast(float, (uint32_t)u << 16);
}

// ---------------------------------------------------------------- converts
__global__ void cvt_plain(const float* __restrict__ src, bf16* __restrict__ dst, int n) {
  int i = (blockIdx.x * 256 + threadIdx.x) * 4;
  if (i >= n) return;
  float4 v = *reinterpret_cast<const float4*>(src + i);
  union { unsigned short u[4]; uint64_t d; } t;
  t.u[0] = bfbits(v.x); t.u[1] = bfbits(v.y); t.u[2] = bfbits(v.z); t.u[3] = bfbits(v.w);
  *reinterpret_cast<uint64_t*>(dst + i) = t.d;
}

// V [B,N,3,512] f32  ->  Vbf [3][B*N][512] bf16
__global__ void cvt_vperm(const float* __restrict__ src, bf16* __restrict__ dst) {
  int g = blockIdx.x * 256 + threadIdx.x;
  int k4  = (g & 127) * 4;
  int rem = g >> 7;                                // (b*2048+n)*3 + c
  int c  = rem % 3;
  int bn = rem / 3;
  float4 v = *reinterpret_cast<const float4*>(src + (size_t)rem * 512 + k4);
  union { unsigned short u[4]; uint64_t d; } t;
  t.u[0] = bfbits(v.x); t.u[1] = bfbits(v.y); t.u[2] = bfbits(v.z); t.u[3] = bfbits(v.w);
  *reinterpret_cast<uint64_t*>(dst + ((size_t)c * 8192 + bn) * 512 + k4) = t.d;
}

__global__ void cvt_weights(const float* __restrict__ wq, const float* __restrict__ wk,
                            const float* __restrict__ wv, const float* __restrict__ wvv,
                            const float* __restrict__ wo, const float* __restrict__ wvo,
                            bf16* __restrict__ dst) {
  int blk = blockIdx.x;
  const float* s; int off;
  if      (blk < 1024) { s = wq  + blk * 1024;          off = 0       + blk * 1024; }
  else if (blk < 2048) { s = wk  + (blk - 1024) * 1024; off = 1048576 + (blk - 1024) * 1024; }
  else if (blk < 2304) { s = wv  + (blk - 2048) * 1024; off = 2097152 + (blk - 2048) * 1024; }
  else if (blk < 2560) { s = wvv + (blk - 2304) * 1024; off = 2359296 + (blk - 2304) * 1024; }
  else if (blk < 2816) { s = wo  + (blk - 2560) * 1024; off = 2621440 + (blk - 2560) * 1024; }
  else                 { s = wvo + (blk - 2816) * 1024; off = 2883584 + (blk - 2816) * 1024; }
  int i = threadIdx.x * 4;
  float4 v = *reinterpret_cast<const float4*>(s + i);
  union { unsigned short u[4]; uint64_t d; } t;
  t.u[0] = bfbits(v.x); t.u[1] = bfbits(v.y); t.u[2] = bfbits(v.z); t.u[3] = bfbits(v.w);
  *reinterpret_cast<uint64_t*>(dst + off + i) = t.d;
}

// Bc[b][n][m] = mask[b][m] ? rbf[b][n][m] + D[b][n][m] : -1e30   (bf16, into d_out)
__global__ void bias_combine(const float* __restrict__ D, const float* __restrict__ rbf,
                             const int* __restrict__ mask, bf16* __restrict__ Bc) {
  size_t i = ((size_t)blockIdx.x * 256 + threadIdx.x) * 4;
  int col = (int)(i & 2047);
  int b   = (int)(i >> 22);
  float4 d = *reinterpret_cast<const float4*>(D + i);
  float4 r = *reinterpret_cast<const float4*>(rbf + i);
  const int* mrow = mask + b * 2048 + col;
  union { unsigned short u[4]; uint64_t dd; } t;
  t.u[0] = mrow[0] ? bfbits(d.x + r.x) : bfbits(-1e30f);
  t.u[1] = mrow[1] ? bfbits(d.y + r.y) : bfbits(-1e30f);
  t.u[2] = mrow[2] ? bfbits(d.z + r.z) : bfbits(-1e30f);
  t.u[3] = mrow[3] ? bfbits(d.w + r.w) : bfbits(-1e30f);
  *reinterpret_cast<uint64_t*>(Bc + i) = t.dd;
}

// ---------------------------------------------------------------- GEMM  C = A @ W^T (+bias)
// MODE 0: -> Q [b,h,n,256] bf16, (acc+bq)*FACTOR      MODE 1: -> K same layout, +bk
// MODE 2: Hv -> Vt[(bh*256+t)*2048 + perm(n)], +bv    MODE 3: Vv -> Vt[.. +64+c*64+t .. perm(n)]
//   (tau key-permutation within each 32-key tile: chunk i -> chunk ((i&3)<<1)|(i>>2))
// MODE 4: -> d_out f32 (+bo)                          MODE 5: -> d_out+4194304 f32
template<int MODE>
__global__ __launch_bounds__(256, 2) void gemm_bt(const bf16* __restrict__ A,
                                                  const bf16* __restrict__ W,
                                                  const float* __restrict__ bias,
                                                  void* __restrict__ outp) {
  constexpr int K = 512;
  __shared__ bf16 As[128][40];
  __shared__ bf16 Bs[128][40];
  const int tid = threadIdx.x;
  const int wid = tid >> 6, lane = tid & 63;
  const int lr = lane & 15, lg = lane >> 4;
  const int wr = wid >> 1, wc = wid & 1;
  const int bm = blockIdx.y * 128, bn = blockIdx.x * 128;
  const int srow = tid >> 2;
  const int scol = (tid & 3) * 8;
  const bf16* Ap = A + (size_t)(bm + srow) * K + scol;
  const bf16* Wp = W + (size_t)(bn + srow) * K + scol;

  f32x4 acc[4][4];
#pragma unroll
  for (int m = 0; m < 4; m++)
#pragma unroll
    for (int n = 0; n < 4; n++) acc[m][n] = (f32x4){0.f, 0.f, 0.f, 0.f};

  bf16x8 a0 = *reinterpret_cast<const bf16x8*>(Ap);
  bf16x8 a1 = *reinterpret_cast<const bf16x8*>(Ap + 64 * K);
  bf16x8 b0 = *reinterpret_cast<const bf16x8*>(Wp);
  bf16x8 b1 = *reinterpret_cast<const bf16x8*>(Wp + 64 * K);

  for (int kt = 0; kt < 16; ++kt) {
    __syncthreads();
    *reinterpret_cast<bf16x8*>(&As[srow][scol])      = a0;
    *reinterpret_cast<bf16x8*>(&As[srow + 64][scol]) = a1;
    *reinterpret_cast<bf16x8*>(&Bs[srow][scol])      = b0;
    *reinterpret_cast<bf16x8*>(&Bs[srow + 64][scol]) = b1;
    __syncthreads();
    if (kt < 15) {
      a0 = *reinterpret_cast<const bf16x8*>(Ap + (kt + 1) * 32);
      a1 = *reinterpret_cast<const bf16x8*>(Ap + (kt + 1) * 32 + 64 * K);
      b0 = *reinterpret_cast<const bf16x8*>(Wp + (kt + 1) * 32);
      b1 = *reinterpret_cast<const bf16x8*>(Wp + (kt + 1) * 32 + 64 * K);
    }
    bf16x8 af[4], bfr[4];
#pragma unroll
    for (int m = 0; m < 4; m++)
      af[m] = *reinterpret_cast<const bf16x8*>(&As[wr * 64 + m * 16 + lr][lg * 8]);
#pragma unroll
    for (int n = 0; n < 4; n++)
      bfr[n] = *reinterpret_cast<const bf16x8*>(&Bs[wc * 64 + n * 16 + lr][lg * 8]);
#pragma unroll
    for (int m = 0; m < 4; m++)
#pragma unroll
      for (int n = 0; n < 4; n++)
        acc[m][n] = __builtin_amdgcn_mfma_f32_16x16x32_bf16(af[m], bfr[n], acc[m][n], 0, 0, 0);
  }

#pragma unroll
  for (int m = 0; m < 4; m++) {
#pragma unroll
    for (int n = 0; n < 4; n++) {
      const int col  = bn + wc * 64 + n * 16 + lr;
      const int row0 = bm + wr * 64 + m * 16 + lg * 4;
      if constexpr (MODE == 0 || MODE == 1) {
        bf16* out = (bf16*)outp;
        const float bb = bias[col];
        const int hh = col >> 8, t = col & 255;
#pragma unroll
        for (int q = 0; q < 4; q++) {
          const int row = row0 + q;
          const int b = row >> 11, nn = row & 2047;
          float v = acc[m][n][q] + bb;
          if constexpr (MODE == 0) v *= FACTOR;
          out[(size_t)((b * 8 + hh) * 2048 + nn) * 256 + t] = __float2bfloat16(v);
        }
      } else if constexpr (MODE == 2 || MODE == 3) {
        bf16* out = (bf16*)outp;
        const int hh = col >> 6, t = col & 63;
        int dimrow, b, nn;
        if constexpr (MODE == 2) {
          b = row0 >> 11; nn = row0 & 2047;
          dimrow = (b * 8 + hh) * 256 + t;
        } else {
          const int c = row0 >> 13; b = (row0 >> 11) & 3; nn = row0 & 2047;
          dimrow = (b * 8 + hh) * 256 + 64 + c * 64 + t;
        }
        // tau key-permutation: 4-key chunk i -> chunk ((i&3)<<1)|(i>>2) within 32-key tile
        const int i4 = (nn >> 2) & 7;
        const int o4 = ((i4 & 3) << 1) | (i4 >> 2);
        const int nn2 = (nn & ~31) | (o4 << 2);
        const float bb = (MODE == 2) ? bias[col] : 0.f;
        union { unsigned short u[4]; uint64_t d; } pk;
#pragma unroll
        for (int q = 0; q < 4; q++) pk.u[q] = bfbits(acc[m][n][q] + bb);
        *reinterpret_cast<uint64_t*>(out + (size_t)dimrow * 2048 + nn2) = pk.d;
      } else {
        float* out = (float*)outp;
        const float bb = (MODE == 4) ? bias[col] : 0.f;
#pragma unroll
        for (int q = 0; q < 4; q++) out[(size_t)(row0 + q) * 512 + col] = acc[m][n][q] + bb;
      }
    }
  }
}

// ---------------------------------------------------------------- flash attention
// grid 256, block 1024 (16 waves x 16 q-rows = 256 q/block). Swapped QK^T: S^T = mfma(K,Q).
// XCD x owns bh in {4x..4x+3} (K/V fetched once per chip); 3-buffer K/V staging with
// counted vmcnt(2) + raw s_barrier (stage t+2 stays in flight across the barrier).
__global__ __launch_bounds__(1024, 4) void attn_kernel(
    const bf16* __restrict__ Qg, const bf16* __restrict__ Kg, const bf16* __restrict__ Vtg,
    const bf16* __restrict__ Bc, bf16* __restrict__ Hres, bf16* __restrict__ Vres) {
  __shared__ bf16 Ks[3 * 32 * 256];   // [key][dim] 512B rows, byte ^= ((row&7)<<4)
  __shared__ bf16 Vs[3 * 32 * 256];   // [dim][key] 64B rows, 16B-chunk ^= ((row>>1)&3), tau keys

  const int g = blockIdx.x;
  const int x = g & 7, loc = g >> 3;
  const int bh = x * 4 + (loc & 3);
  const int qt = loc >> 2;
  const int b = bh >> 3, h = bh & 7;
  const int tid = threadIdx.x, w = tid >> 6, lane = tid & 63;
  const int lr = lane & 15, lg = lane >> 4;
  const int q0 = qt * 256 + w * 16;

  const bf16* Qb = Qg + (size_t)bh * 2048 * 256;
  const bf16* Kb = Kg + (size_t)bh * 2048 * 256;
  const bf16* Vb = Vtg + (size_t)bh * 256 * 2048;
  const bf16* Bbase = Bc + ((size_t)(b * 2048 + q0 + lr)) * 2048 + lg * 4;

  bf16x8 qf[8];
#pragma unroll
  for (int kc = 0; kc < 8; kc++)
    qf[kc] = *reinterpret_cast<const bf16x8*>(Qb + (size_t)(q0 + lr) * 256 + kc * 32 + lg * 8);

  f32x4 O[16];
#pragma unroll
  for (int dc = 0; dc < 16; dc++) O[dc] = (f32x4){0.f, 0.f, 0.f, 0.f};
  float mrun = -INFINITY, lrun = 0.f;   // per-lane state for q-row = q0 + lr

  // staging sources: wave w stages bytes [w*1024, w*1024+1024) of each 16KB tile
  const int kX = w * 1024 + lane * 16;
  const int krow = kX >> 9, kcol = kX & 511;
  const char* ksrc = (const char*)Kb + (size_t)krow * 512 + (kcol ^ ((krow & 7) << 4));
  const int vrow = kX >> 6;
  const char* vsrc = (const char*)Vb + (size_t)vrow * 4096 + (((lane & 3) ^ ((lane >> 3) & 3)) << 4);
  char* ldsKw = (char*)Ks + w * 1024;   // + buf*16384
  char* ldsVw = (char*)Vs + w * 1024;

  // PV read column chunk (dc-independent): slot-distinct XOR
  const int vblk_r = (lg ^ ((lr >> 1) & 3)) << 4;

  // prologue: bias(0) + stage tiles 0,1 into bufs 0,1
  u16x4 ba_c = *reinterpret_cast<const u16x4*>(Bbase);
  u16x4 bb_c = *reinterpret_cast<const u16x4*>(Bbase + 16);
  __builtin_amdgcn_global_load_lds(ksrc, ldsKw, 16, 0, 0);
  __builtin_amdgcn_global_load_lds(vsrc, ldsVw, 16, 0, 0);
  __builtin_amdgcn_global_load_lds(ksrc + 16384, ldsKw + 16384, 16, 0, 0);
  __builtin_amdgcn_global_load_lds(vsrc + 64,   ldsVw + 16384, 16, 0, 0);
  asm volatile("s_waitcnt vmcnt(2)" ::: "memory");
  __builtin_amdgcn_sched_barrier(0);
  __builtin_amdgcn_s_barrier();

  int c0 = 0;   // compute buffer
  int cs = 2;   // stage buffer = (kt+2)%3

  for (int kt = 0; kt < 64; ++kt) {
    // bias(t+1) -> regs (not counted by the end-of-iter vmcnt: issued before stages)
    u16x4 ba_n = ba_c, bb_n = bb_c;
    if (kt < 63) {
      ba_n = *reinterpret_cast<const u16x4*>(Bbase + (kt + 1) * 32);
      bb_n = *reinterpret_cast<const u16x4*>(Bbase + (kt + 1) * 32 + 16);
    }
    __builtin_amdgcn_sched_barrier(0);
    // stage tile t+2
    if (kt < 62) {
      __builtin_amdgcn_global_load_lds(ksrc + (size_t)(kt + 2) * 16384, ldsKw + cs * 16384, 16, 0, 0);
      __builtin_amdgcn_global_load_lds(vsrc + (size_t)(kt + 2) * 64,    ldsVw + cs * 16384, 16, 0, 0);
    }
    __builtin_amdgcn_sched_barrier(0);

    // ---- compute tile t on buffer c0 ----
    const char* KsC = (const char*)Ks + c0 * 16384;
    f32x4 s_a = (f32x4){0.f, 0.f, 0.f, 0.f}, s_b = (f32x4){0.f, 0.f, 0.f, 0.f};
#pragma unroll
    for (int kc = 0; kc < 8; kc++) {
      const int cb = (kc * 64 + lg * 16) ^ ((lr & 7) << 4);
      bf16x8 k0f = *reinterpret_cast<const bf16x8*>(KsC + lr * 512 + cb);
      bf16x8 k1f = *reinterpret_cast<const bf16x8*>(KsC + (16 + lr) * 512 + cb);
      s_a = __builtin_amdgcn_mfma_f32_16x16x32_bf16(k0f, qf[kc], s_a, 0, 0, 0);
      s_b = __builtin_amdgcn_mfma_f32_16x16x32_bf16(k1f, qf[kc], s_b, 0, 0, 0);
    }
    float sc[8];
#pragma unroll
    for (int r = 0; r < 4; r++) {
      sc[r]     = s_a[r] + b2f((unsigned short)ba_c[r]);
      sc[r + 4] = s_b[r] + b2f((unsigned short)bb_c[r]);
    }

    // row max: in-lane 8 + xor16 + xor32 (lanes lr,lr+16,lr+32,lr+48 share q-row)
    float pmax = fmaxf(fmaxf(fmaxf(sc[0], sc[1]), fmaxf(sc[2], sc[3])),
                       fmaxf(fmaxf(sc[4], sc[5]), fmaxf(sc[6], sc[7])));
    pmax = fmaxf(pmax, __shfl_xor(pmax, 16));
    pmax = fmaxf(pmax, __shfl_xor(pmax, 32));

    // defer-max (THR=8)
    const bool ok = (pmax <= mrun + 8.f);
    if (!__all((int)ok)) {
      const float mnew = fmaxf(mrun, pmax);
      const float scq = __expf(mrun - mnew);
      lrun *= scq;
      mrun = mnew;
      float so[4];
#pragma unroll
      for (int r = 0; r < 4; r++) so[r] = __shfl(scq, lg * 4 + r);
#pragma unroll
      for (int dc = 0; dc < 16; dc++) {
#pragma unroll
        for (int r = 0; r < 4; r++) O[dc][r] *= so[r];
      }
    }

    // exp + pack PA fragment (tau ordering makes register order == A-frag order)
    union { unsigned short u[8]; bf16x8 v; } pk;
    float rs = 0.f;
#pragma unroll
    for (int j = 0; j < 8; j++) {
      const float p = __expf(sc[j] - mrun);
      const bf16 ph = __float2bfloat16(p);
      pk.u[j] = __builtin_bit_cast(unsigned short, ph);
      rs += __bfloat162float(ph);
    }
    rs += __shfl_xor(rs, 16);
    rs += __shfl_xor(rs, 32);
    lrun += rs;

    // PV: O[q][dim] += P @ V
    const char* VsC = (const char*)Vs + c0 * 16384;
#pragma unroll
    for (int dc = 0; dc < 16; dc++) {
      bf16x8 vf = *reinterpret_cast<const bf16x8*>(VsC + (dc * 16 + lr) * 64 + vblk_r);
      O[dc] = __builtin_amdgcn_mfma_f32_16x16x32_bf16(pk.v, vf, O[dc], 0, 0, 0);
    }

    // counted wait: keep stage(t+2) in flight, guarantee stage(t+1) landed; then barrier
    asm volatile("s_waitcnt vmcnt(2)" ::: "memory");
    __builtin_amdgcn_sched_barrier(0);
    __builtin_amdgcn_s_barrier();

    c0 = (c0 == 2) ? 0 : c0 + 1;
    cs = (cs == 2) ? 0 : cs + 1;
    ba_c = ba_n; bb_c = bb_n;
  }

  // epilogue: O lane (lr,lg) holds dims dc*16+lr, q-rows q0+lg*4+r
  const float rli = 1.0f / lrun;
  float rl[4];
#pragma unroll
  for (int r = 0; r < 4; r++) rl[r] = __shfl(rli, lg * 4 + r);
#pragma unroll
  for (int dc = 0; dc < 16; dc++) {
    const int cd = dc * 16 + lr;
#pragma unroll
    for (int r = 0; r < 4; r++) {
      const int row = q0 + lg * 4 + r;
      const float v = O[dc][r] * rl[r];
      if (cd < 64) {
        Hres[(size_t)(b * 2048 + row) * 512 + h * 64 + cd] = __float2bfloat16(v);
      } else {
        const int c = (cd - 64) >> 6, t = (cd - 64) & 63;
        Vres[((size_t)(b * 2048 + row) * 3 + c) * 512 + h * 64 + t] = __float2bfloat16(v);
      }
    }
  }
}

// ---------------------------------------------------------------- launch
extern "C" void kernel_launch(void* const* d_in, const int* in_sizes, int n_in,
                              void* d_out, int out_size, void* d_ws, size_t ws_size,
                              hipStream_t stream) {
  const float* H   = (const float*)d_in[0];
  const float* V   = (const float*)d_in[1];
  const float* Dm  = (const float*)d_in[2];
  const float* rbf = (const float*)d_in[3];
  const int*   mask= (const int*)d_in[4];
  const float* Wq  = (const float*)d_in[5];
  const float* bq  = (const float*)d_in[6];
  const float* Wk  = (const float*)d_in[7];
  const float* bk  = (const float*)d_in[8];
  const float* Wv  = (const float*)d_in[9];
  const float* bv  = (const float*)d_in[10];
  const float* Wvv = (const float*)d_in[11];
  const float* Wo  = (const float*)d_in[12];
  const float* bo  = (const float*)d_in[13];
  const float* Wvo = (const float*)d_in[14];

  char* ws = (char*)d_ws;
  bf16* Hbf  = (bf16*)(ws);                    // aliased by Hres after last read
  bf16* Vbf  = (bf16*)(ws + 8388608);          // aliased by Vres after last read
  bf16* Wall = (bf16*)(ws + 33554432);
  bf16* Qw   = (bf16*)(ws + 39845888);
  bf16* Kw   = (bf16*)(ws + 73400320);
  bf16* Vtw  = (bf16*)(ws + 106954752);
  bf16* Hres = Hbf;
  bf16* Vres = Vbf;
  bf16* Wqb  = Wall;
  bf16* Wkb  = Wall + 1048576;
  bf16* Wvb  = Wall + 2097152;
  bf16* Wvvb = Wall + 2359296;
  bf16* Wob  = Wall + 2621440;
  bf16* Wvob = Wall + 2883584;
  bf16* Bcb  = (bf16*)d_out;                   // 33.5MB bf16 in d_out; read fully by attn
                                               // before the final GEMMs overwrite d_out

  bias_combine<<<16384, 256, 0, stream>>>(Dm, rbf, mask, Bcb);
  cvt_plain<<<4096, 256, 0, stream>>>(H, Hbf, 4194304);
  cvt_vperm<<<12288, 256, 0, stream>>>(V, Vbf);
  cvt_weights<<<3072, 256, 0, stream>>>(Wq, Wk, Wv, Wvv, Wo, Wvo, Wall);

  gemm_bt<0><<<dim3(16, 64), 256, 0, stream>>>(Hbf, Wqb, bq, Qw);
  gemm_bt<1><<<dim3(16, 64), 256, 0, stream>>>(Hbf, Wkb, bk, Kw);
  gemm_bt<2><<<dim3(4, 64), 256, 0, stream>>>(Hbf, Wvb, bv, Vtw);
  gemm_bt<3><<<dim3(4, 192), 256, 0, stream>>>(Vbf, Wvvb, nullptr, Vtw);

  attn_kernel<<<256, 1024, 0, stream>>>(Qw, Kw, Vtw, Bcb, Hres, Vres);

  gemm_bt<4><<<dim3(4, 64), 256, 0, stream>>>(Hres, Wob, bo, d_out);
  gemm_bt<5><<<dim3(4, 192), 256, 0, stream>>>(Vres, Wvob, nullptr, (float*)d_out + 4194304);
}

// Round 6
// 442.672 us; speedup vs baseline: 2.1709x; 1.2774x over previous
//
#include <hip/hip_runtime.h>
#include <hip/hip_bf16.h>
#include <stdint.h>

typedef __hip_bfloat16 bf16;
typedef __attribute__((ext_vector_type(8))) short bf16x8;   // 8 bf16 = 4 VGPRs
typedef __attribute__((ext_vector_type(4))) float f32x4;
typedef __attribute__((ext_vector_type(16))) float f32x16;
typedef __attribute__((ext_vector_type(4))) unsigned short u16x4;

#define DEVI __device__ __forceinline__

static constexpr float FACTOR = 0.0625f;  // 0.5 / sqrt(64)

DEVI unsigned short bfbits(float x) {
  return __builtin_bit_cast(unsigned short, __float2bfloat16(x));
}
DEVI float b2f(unsigned short u) {
  return __builtin_bit_cast(float, (uint32_t)u << 16);
}

// ---------------------------------------------------------------- converts
__global__ void cvt_plain(const float* __restrict__ src, bf16* __restrict__ dst, int n) {
  int i = (blockIdx.x * 256 + threadIdx.x) * 4;
  if (i >= n) return;
  float4 v = *reinterpret_cast<const float4*>(src + i);
  union { unsigned short u[4]; uint64_t d; } t;
  t.u[0] = bfbits(v.x); t.u[1] = bfbits(v.y); t.u[2] = bfbits(v.z); t.u[3] = bfbits(v.w);
  *reinterpret_cast<uint64_t*>(dst + i) = t.d;
}

// V [B,N,3,512] f32  ->  Vbf [3][B*N][512] bf16
__global__ void cvt_vperm(const float* __restrict__ src, bf16* __restrict__ dst) {
  int g = blockIdx.x * 256 + threadIdx.x;
  int k4  = (g & 127) * 4;
  int rem = g >> 7;                                // (b*2048+n)*3 + c
  int c  = rem % 3;
  int bn = rem / 3;
  float4 v = *reinterpret_cast<const float4*>(src + (size_t)rem * 512 + k4);
  union { unsigned short u[4]; uint64_t d; } t;
  t.u[0] = bfbits(v.x); t.u[1] = bfbits(v.y); t.u[2] = bfbits(v.z); t.u[3] = bfbits(v.w);
  *reinterpret_cast<uint64_t*>(dst + ((size_t)c * 8192 + bn) * 512 + k4) = t.d;
}

__global__ void cvt_weights(const float* __restrict__ wq, const float* __restrict__ wk,
                            const float* __restrict__ wv, const float* __restrict__ wvv,
                            const float* __restrict__ wo, const float* __restrict__ wvo,
                            bf16* __restrict__ dst) {
  int blk = blockIdx.x;
  const float* s; int off;
  if      (blk < 1024) { s = wq  + blk * 1024;          off = 0       + blk * 1024; }
  else if (blk < 2048) { s = wk  + (blk - 1024) * 1024; off = 1048576 + (blk - 1024) * 1024; }
  else if (blk < 2304) { s = wv  + (blk - 2048) * 1024; off = 2097152 + (blk - 2048) * 1024; }
  else if (blk < 2560) { s = wvv + (blk - 2304) * 1024; off = 2359296 + (blk - 2304) * 1024; }
  else if (blk < 2816) { s = wo  + (blk - 2560) * 1024; off = 2621440 + (blk - 2560) * 1024; }
  else                 { s = wvo + (blk - 2816) * 1024; off = 2883584 + (blk - 2816) * 1024; }
  int i = threadIdx.x * 4;
  float4 v = *reinterpret_cast<const float4*>(s + i);
  union { unsigned short u[4]; uint64_t d; } t;
  t.u[0] = bfbits(v.x); t.u[1] = bfbits(v.y); t.u[2] = bfbits(v.z); t.u[3] = bfbits(v.w);
  *reinterpret_cast<uint64_t*>(dst + off + i) = t.d;
}

// Bc[b][n][m] = mask[b][m] ? rbf[b][n][m] + D[b][n][m] : -1e30   (bf16, into d_out)
__global__ void bias_combine(const float* __restrict__ D, const float* __restrict__ rbf,
                             const int* __restrict__ mask, bf16* __restrict__ Bc) {
  size_t i = ((size_t)blockIdx.x * 256 + threadIdx.x) * 4;
  int col = (int)(i & 2047);
  int b   = (int)(i >> 22);
  float4 d = *reinterpret_cast<const float4*>(D + i);
  float4 r = *reinterpret_cast<const float4*>(rbf + i);
  const int* mrow = mask + b * 2048 + col;
  union { unsigned short u[4]; uint64_t dd; } t;
  t.u[0] = mrow[0] ? bfbits(d.x + r.x) : bfbits(-1e30f);
  t.u[1] = mrow[1] ? bfbits(d.y + r.y) : bfbits(-1e30f);
  t.u[2] = mrow[2] ? bfbits(d.z + r.z) : bfbits(-1e30f);
  t.u[3] = mrow[3] ? bfbits(d.w + r.w) : bfbits(-1e30f);
  *reinterpret_cast<uint64_t*>(Bc + i) = t.dd;
}

// ---------------------------------------------------------------- GEMM  C = A @ W^T (+bias)
// MODE 0: -> Q [b,h,n,256] bf16, (acc+bq)*FACTOR      MODE 1: -> K same layout, +bk
// MODE 2: Hv -> Vt[(bh*256+t)*2048 + perm(n)], +bv    MODE 3: Vv -> Vt[.. +64+c*64+t .. perm(n)]
//   key permutation per 32-key tile (4-key chunks): o4 = (i4&4)|((i4&1)<<1)|((i4>>1)&1)
//   => stored column order matches the 32x32 MFMA C/D key residence (kr = (r&3)+8(r>>2)+4hi),
//      so softmax P registers pack directly into the PV A-fragment (no cross-lane exchange).
// MODE 4: -> d_out f32 (+bo)                          MODE 5: -> d_out+4194304 f32
template<int MODE>
__global__ __launch_bounds__(256, 2) void gemm_bt(const bf16* __restrict__ A,
                                                  const bf16* __restrict__ W,
                                                  const float* __restrict__ bias,
                                                  void* __restrict__ outp) {
  constexpr int K = 512;
  __shared__ bf16 As[128][40];
  __shared__ bf16 Bs[128][40];
  const int tid = threadIdx.x;
  const int wid = tid >> 6, lane = tid & 63;
  const int lr = lane & 15, lg = lane >> 4;
  const int wr = wid >> 1, wc = wid & 1;
  const int bm = blockIdx.y * 128, bn = blockIdx.x * 128;
  const int srow = tid >> 2;
  const int scol = (tid & 3) * 8;
  const bf16* Ap = A + (size_t)(bm + srow) * K + scol;
  const bf16* Wp = W + (size_t)(bn + srow) * K + scol;

  f32x4 acc[4][4];
#pragma unroll
  for (int m = 0; m < 4; m++)
#pragma unroll
    for (int n = 0; n < 4; n++) acc[m][n] = (f32x4){0.f, 0.f, 0.f, 0.f};

  bf16x8 a0 = *reinterpret_cast<const bf16x8*>(Ap);
  bf16x8 a1 = *reinterpret_cast<const bf16x8*>(Ap + 64 * K);
  bf16x8 b0 = *reinterpret_cast<const bf16x8*>(Wp);
  bf16x8 b1 = *reinterpret_cast<const bf16x8*>(Wp + 64 * K);

  for (int kt = 0; kt < 16; ++kt) {
    __syncthreads();
    *reinterpret_cast<bf16x8*>(&As[srow][scol])      = a0;
    *reinterpret_cast<bf16x8*>(&As[srow + 64][scol]) = a1;
    *reinterpret_cast<bf16x8*>(&Bs[srow][scol])      = b0;
    *reinterpret_cast<bf16x8*>(&Bs[srow + 64][scol]) = b1;
    __syncthreads();
    if (kt < 15) {
      a0 = *reinterpret_cast<const bf16x8*>(Ap + (kt + 1) * 32);
      a1 = *reinterpret_cast<const bf16x8*>(Ap + (kt + 1) * 32 + 64 * K);
      b0 = *reinterpret_cast<const bf16x8*>(Wp + (kt + 1) * 32);
      b1 = *reinterpret_cast<const bf16x8*>(Wp + (kt + 1) * 32 + 64 * K);
    }
    bf16x8 af[4], bfr[4];
#pragma unroll
    for (int m = 0; m < 4; m++)
      af[m] = *reinterpret_cast<const bf16x8*>(&As[wr * 64 + m * 16 + lr][lg * 8]);
#pragma unroll
    for (int n = 0; n < 4; n++)
      bfr[n] = *reinterpret_cast<const bf16x8*>(&Bs[wc * 64 + n * 16 + lr][lg * 8]);
#pragma unroll
    for (int m = 0; m < 4; m++)
#pragma unroll
      for (int n = 0; n < 4; n++)
        acc[m][n] = __builtin_amdgcn_mfma_f32_16x16x32_bf16(af[m], bfr[n], acc[m][n], 0, 0, 0);
  }

#pragma unroll
  for (int m = 0; m < 4; m++) {
#pragma unroll
    for (int n = 0; n < 4; n++) {
      const int col  = bn + wc * 64 + n * 16 + lr;
      const int row0 = bm + wr * 64 + m * 16 + lg * 4;
      if constexpr (MODE == 0 || MODE == 1) {
        bf16* out = (bf16*)outp;
        const float bb = bias[col];
        const int hh = col >> 8, t = col & 255;
#pragma unroll
        for (int q = 0; q < 4; q++) {
          const int row = row0 + q;
          const int b = row >> 11, nn = row & 2047;
          float v = acc[m][n][q] + bb;
          if constexpr (MODE == 0) v *= FACTOR;
          out[(size_t)((b * 8 + hh) * 2048 + nn) * 256 + t] = __float2bfloat16(v);
        }
      } else if constexpr (MODE == 2 || MODE == 3) {
        bf16* out = (bf16*)outp;
        const int hh = col >> 6, t = col & 63;
        int dimrow, b, nn;
        if constexpr (MODE == 2) {
          b = row0 >> 11; nn = row0 & 2047;
          dimrow = (b * 8 + hh) * 256 + t;
        } else {
          const int c = row0 >> 13; b = (row0 >> 11) & 3; nn = row0 & 2047;
          dimrow = (b * 8 + hh) * 256 + 64 + c * 64 + t;
        }
        // key-column permutation (see header comment); nn is 4-aligned
        const int i4 = (nn >> 2) & 7;
        const int o4 = (i4 & 4) | ((i4 & 1) << 1) | ((i4 >> 1) & 1);
        const int nn2 = (nn & ~31) | (o4 << 2);
        const float bb = (MODE == 2) ? bias[col] : 0.f;
        union { unsigned short u[4]; uint64_t d; } pk;
#pragma unroll
        for (int q = 0; q < 4; q++) pk.u[q] = bfbits(acc[m][n][q] + bb);
        *reinterpret_cast<uint64_t*>(out + (size_t)dimrow * 2048 + nn2) = pk.d;
      } else {
        float* out = (float*)outp;
        const float bb = (MODE == 4) ? bias[col] : 0.f;
#pragma unroll
        for (int q = 0; q < 4; q++) out[(size_t)(row0 + q) * 512 + col] = acc[m][n][q] + bb;
      }
    }
  }
}

// ---------------------------------------------------------------- flash attention
// grid 512, block 256 (4 waves x 32 q-rows = 128 q/block), 2 blocks/CU.
// 32x32x16 MFMA. Swapped QK^T: S^T = mfma(K, Q) -> lane holds q = lane&31, 16 keys at
// kr(r) = (r&3)+8*(r>>2)+4*hi. V keys stored pre-permuted to match -> P packs directly
// into the PV A-fragment (no cross-lane ops). Always-rescale online softmax.
// XCD x owns bh in {4x..4x+3}. K/V double-buffered LDS via global_load_lds.
__global__ __launch_bounds__(256, 2) void attn_kernel(
    const bf16* __restrict__ Qg, const bf16* __restrict__ Kg, const bf16* __restrict__ Vtg,
    const bf16* __restrict__ Bc, bf16* __restrict__ Hres, bf16* __restrict__ Vres) {
  __shared__ bf16 Ks[2][32 * 256];   // [key][dim] 512B rows, 16B-chunk ^= (key&31)
  __shared__ bf16 Vs[2][256 * 32];   // [dim][key] 64B rows, chunk ^= gg(row); perm'd key cols

  const int g = blockIdx.x;
  const int x = g & 7, loc = g >> 3;            // loc 0..63
  const int bh = x * 4 + (loc & 3);
  const int qt = loc >> 2;                       // 0..15
  const int b = bh >> 3, h = bh & 7;
  const int tid = threadIdx.x, w = tid >> 6, lane = tid & 63;
  const int lq = lane & 31, hi = lane >> 5;
  const int q0 = qt * 128 + w * 32;

  const bf16* Qb = Qg + (size_t)bh * 2048 * 256;
  const char* KbC = (const char*)(Kg + (size_t)bh * 2048 * 256);
  const char* VbC = (const char*)(Vtg + (size_t)bh * 256 * 2048);
  const bf16* Bb = Bc + ((size_t)(b * 2048 + q0 + lq)) * 2048 + hi * 4;

  // Q fragments: B-operand of mfma(K,Q): lane -> col q = lq, k-positions hi*8..+7
  bf16x8 qf[16];
#pragma unroll
  for (int kc = 0; kc < 16; kc++)
    qf[kc] = *reinterpret_cast<const bf16x8*>(Qb + (size_t)(q0 + lq) * 256 + kc * 16 + hi * 8);

  f32x16 O[8];
#pragma unroll
  for (int dt = 0; dt < 8; dt++)
#pragma unroll
    for (int r = 0; r < 16; r++) O[dt][r] = 0.f;
  float mrun = -INFINITY, lrun = 0.f;   // per-lane state for q-row q0 + lq

  // ---- staging addresses (4 gload_lds each for K and V per wave) ----
  const char* ksrc[4]; const char* vsrc[4];
#pragma unroll
  for (int i = 0; i < 4; i++) {
    const int krow = w * 8 + 2 * i + hi;
    ksrc[i] = KbC + (size_t)krow * 512 + ((lq * 16) ^ ((krow & 31) << 4));
    const int vrow = w * 64 + i * 16 + (lane >> 2);
    const int gg = ((vrow >> 1) ^ (vrow >> 3)) & 3;
    vsrc[i] = VbC + (size_t)vrow * 4096 + (((lane & 3) ^ gg) << 4);
  }

  // prologue: stage tile 0 into buf 0
  {
    char* dK = (char*)&Ks[0][0] + w * 4096;
    char* dV = (char*)&Vs[0][0] + w * 4096;
#pragma unroll
    for (int i = 0; i < 4; i++) {
      __builtin_amdgcn_global_load_lds(ksrc[i], dK + i * 1024, 16, 0, 0);
      __builtin_amdgcn_global_load_lds(vsrc[i], dV + i * 1024, 16, 0, 0);
    }
  }
  asm volatile("s_waitcnt vmcnt(0)" ::: "memory");
  __builtin_amdgcn_sched_barrier(0);
  __builtin_amdgcn_s_barrier();

  for (int kt = 0; kt < 64; ++kt) {
    const int cur = kt & 1;
    // bias for current tile: bg[i][j] = bias[q0+lq][kt*32 + 4hi + 8i + j] = key kr(i*4+j)
    u16x4 bg[4];
#pragma unroll
    for (int i = 0; i < 4; i++)
      bg[i] = *reinterpret_cast<const u16x4*>(Bb + kt * 32 + i * 8);
    // stage tile t+1 into the other buffer
    if (kt < 63) {
      char* dK = (char*)&Ks[cur ^ 1][0] + w * 4096;
      char* dV = (char*)&Vs[cur ^ 1][0] + w * 4096;
#pragma unroll
      for (int i = 0; i < 4; i++) {
        __builtin_amdgcn_global_load_lds(ksrc[i] + (size_t)(kt + 1) * 16384, dK + i * 1024, 16, 0, 0);
        __builtin_amdgcn_global_load_lds(vsrc[i] + (size_t)(kt + 1) * 64,    dV + i * 1024, 16, 0, 0);
      }
    }
    __builtin_amdgcn_sched_barrier(0);

    // ---- S^T = K @ Q^T on buf cur ----
    const char* KsC = (const char*)&Ks[cur][0];
    f32x16 s;
#pragma unroll
    for (int r = 0; r < 16; r++) s[r] = 0.f;
    const int kxor = lq << 4;
#pragma unroll
    for (int kc = 0; kc < 16; kc++) {
      bf16x8 kf = *reinterpret_cast<const bf16x8*>(KsC + lq * 512 + ((kc * 32 + hi * 16) ^ kxor));
      s = __builtin_amdgcn_mfma_f32_32x32x16_bf16(kf, qf[kc], s, 0, 0, 0);
    }
    // + bias (bg dead after this)
#pragma unroll
    for (int r = 0; r < 16; r++)
      s[r] += b2f((unsigned short)bg[r >> 2][r & 3]);

    // row max: 16 in-lane + xor32 (lanes lq, lq+32 share q-row)
    float pmax = s[0];
#pragma unroll
    for (int r = 1; r < 16; r++) pmax = fmaxf(pmax, s[r]);
    pmax = fmaxf(pmax, __shfl_xor(pmax, 32));

    // online-softmax rescale (always)
    const float mnew = fmaxf(mrun, pmax);
    const float scq = __expf(mrun - mnew);
    mrun = mnew;
    lrun *= scq;
    float sfac[16];
#pragma unroll
    for (int r = 0; r < 16; r++) sfac[r] = __shfl(scq, (r & 3) + 8 * (r >> 2) + 4 * hi);
#pragma unroll
    for (int dt = 0; dt < 8; dt++)
#pragma unroll
      for (int r = 0; r < 16; r++) O[dt][r] *= sfac[r];

    // exp + direct pack into PV A-fragments (V key columns pre-permuted to match)
    union { unsigned short u[8]; bf16x8 v; } pa0, pa1;
    float rs = 0.f;
#pragma unroll
    for (int j = 0; j < 8; j++) {
      const float p = __expf(s[j] - mrun);
      pa0.u[j] = bfbits(p);
      rs += b2f(pa0.u[j]);
    }
#pragma unroll
    for (int j = 0; j < 8; j++) {
      const float p = __expf(s[8 + j] - mrun);
      pa1.u[j] = bfbits(p);
      rs += b2f(pa1.u[j]);
    }
    rs += __shfl_xor(rs, 32);
    lrun += rs;

    // ---- PV: O[q][dim] += P @ V on buf cur ----
    const char* VsC = (const char*)&Vs[cur][0];
#pragma unroll
    for (int dt = 0; dt < 8; dt++) {
      const int row = dt * 32 + lq;
      const int gg = ((row >> 1) ^ (row >> 3)) & 3;
      bf16x8 v0 = *reinterpret_cast<const bf16x8*>(VsC + row * 64 + ((hi ^ gg) << 4));
      bf16x8 v1 = *reinterpret_cast<const bf16x8*>(VsC + row * 64 + (((2 + hi) ^ gg) << 4));
      O[dt] = __builtin_amdgcn_mfma_f32_32x32x16_bf16(pa0.v, v0, O[dt], 0, 0, 0);
      O[dt] = __builtin_amdgcn_mfma_f32_32x32x16_bf16(pa1.v, v1, O[dt], 0, 0, 0);
    }

    if (kt < 63) {
      asm volatile("s_waitcnt vmcnt(0)" ::: "memory");
      __builtin_amdgcn_sched_barrier(0);
      __builtin_amdgcn_s_barrier();
    }
  }

  // epilogue: O[dt] col = dim dt*32+lq, rows = q kr(r)
  const float rli = 1.0f / lrun;
  float rl[16];
#pragma unroll
  for (int r = 0; r < 16; r++) rl[r] = __shfl(rli, (r & 3) + 8 * (r >> 2) + 4 * hi);
#pragma unroll
  for (int dt = 0; dt < 8; dt++) {
    const int d = dt * 32 + lq;
#pragma unroll
    for (int r = 0; r < 16; r++) {
      const int row = q0 + (r & 3) + 8 * (r >> 2) + 4 * hi;
      const float v = O[dt][r] * rl[r];
      if (d < 64) {
        Hres[(size_t)(b * 2048 + row) * 512 + h * 64 + d] = __float2bfloat16(v);
      } else {
        const int c = (d - 64) >> 6, t = (d - 64) & 63;
        Vres[((size_t)(b * 2048 + row) * 3 + c) * 512 + h * 64 + t] = __float2bfloat16(v);
      }
    }
  }
}

// ---------------------------------------------------------------- launch
extern "C" void kernel_launch(void* const* d_in, const int* in_sizes, int n_in,
                              void* d_out, int out_size, void* d_ws, size_t ws_size,
                              hipStream_t stream) {
  const float* H   = (const float*)d_in[0];
  const float* V   = (const float*)d_in[1];
  const float* Dm  = (const float*)d_in[2];
  const float* rbf = (const float*)d_in[3];
  const int*   mask= (const int*)d_in[4];
  const float* Wq  = (const float*)d_in[5];
  const float* bq  = (const float*)d_in[6];
  const float* Wk  = (const float*)d_in[7];
  const float* bk  = (const float*)d_in[8];
  const float* Wv  = (const float*)d_in[9];
  const float* bv  = (const float*)d_in[10];
  const float* Wvv = (const float*)d_in[11];
  const float* Wo  = (const float*)d_in[12];
  const float* bo  = (const float*)d_in[13];
  const float* Wvo = (const float*)d_in[14];

  char* ws = (char*)d_ws;
  bf16* Hbf  = (bf16*)(ws);                    // aliased by Hres after last read
  bf16* Vbf  = (bf16*)(ws + 8388608);          // aliased by Vres after last read
  bf16* Wall = (bf16*)(ws + 33554432);
  bf16* Qw   = (bf16*)(ws + 39845888);
  bf16* Kw   = (bf16*)(ws + 73400320);
  bf16* Vtw  = (bf16*)(ws + 106954752);
  bf16* Hres = Hbf;
  bf16* Vres = Vbf;
  bf16* Wqb  = Wall;
  bf16* Wkb  = Wall + 1048576;
  bf16* Wvb  = Wall + 2097152;
  bf16* Wvvb = Wall + 2359296;
  bf16* Wob  = Wall + 2621440;
  bf16* Wvob = Wall + 2883584;
  bf16* Bcb  = (bf16*)d_out;                   // 33.5MB bf16 in d_out; read fully by attn
                                               // before the final GEMMs overwrite d_out

  bias_combine<<<16384, 256, 0, stream>>>(Dm, rbf, mask, Bcb);
  cvt_plain<<<4096, 256, 0, stream>>>(H, Hbf, 4194304);
  cvt_vperm<<<12288, 256, 0, stream>>>(V, Vbf);
  cvt_weights<<<3072, 256, 0, stream>>>(Wq, Wk, Wv, Wvv, Wo, Wvo, Wall);

  gemm_bt<0><<<dim3(16, 64), 256, 0, stream>>>(Hbf, Wqb, bq, Qw);
  gemm_bt<1><<<dim3(16, 64), 256, 0, stream>>>(Hbf, Wkb, bk, Kw);
  gemm_bt<2><<<dim3(4, 64), 256, 0, stream>>>(Hbf, Wvb, bv, Vtw);
  gemm_bt<3><<<dim3(4, 192), 256, 0, stream>>>(Vbf, Wvvb, nullptr, Vtw);

  attn_kernel<<<512, 256, 0, stream>>>(Qw, Kw, Vtw, Bcb, Hres, Vres);

  gemm_bt<4><<<dim3(4, 64), 256, 0, stream>>>(Hres, Wob, bo, d_out);
  gemm_bt<5><<<dim3(4, 192), 256, 0, stream>>>(Vres, Wvob, nullptr, (float*)d_out + 4194304);
}